// Round 7
// baseline (209.336 us; speedup 1.0000x reference)
//
#include <hip/hip_runtime.h>
#include <math.h>

#define SEQ   4096
#define NOBJ  32
#define IN_F  4
#define HID   64
#define IFEAT 8
#define NPAIR_HALF 496   // 32*31/2 unordered pairs

#define TWO_LOG2E 2.8853900817779268f   // 2*log2(e)

#if __has_builtin(__builtin_amdgcn_exp2f)
  #define EXP2F(x) __builtin_amdgcn_exp2f(x)
#else
  #define EXP2F(x) exp2f(x)
#endif

typedef _Float16 h2 __attribute__((ext_vector_type(2)));

__device__ __forceinline__ h2 pack2(float a, float b) {
#if __has_builtin(__builtin_amdgcn_cvt_pkrtz)
  return __builtin_bit_cast(h2, __builtin_amdgcn_cvt_pkrtz(a, b));
#else
  h2 r; r.x = (_Float16)a; r.y = (_Float16)b; return r;
#endif
}

// 2-way f16 dot with fp32 accumulate: v_dot2_f32_f16 (1 issue = 2 MACs)
__device__ __forceinline__ float fdot2f(h2 a, h2 b, float c) {
#if __has_builtin(__builtin_amdgcn_fdot2)
  return __builtin_amdgcn_fdot2(a, b, c, false);
#else
  return fmaf((float)a.x, (float)b.x, fmaf((float)a.y, (float)b.y, c));
#endif
}

__device__ __forceinline__ h2 asb(int v) { return __builtin_bit_cast(h2, v); }

// tanh via exp2: tanh(x) = 1 - 2/(exp2(x*2log2e)+1)
__device__ __forceinline__ float tanh_u(float x) {
  float e = EXP2F(x * TWO_LOG2E);
  float r = __builtin_amdgcn_rcpf(e + 1.0f);
  return fmaf(-2.0f, r, 1.0f);
}

// cumulative pair count before row i (i<j ordering): C(i) = i*(63-i)/2
__device__ __forceinline__ int pair_cum(int i) { return (i * (63 - i)) >> 1; }

__device__ __forceinline__ void pair_decode(int q, int& i, int& j) {
  int ii = (int)((63.0f - sqrtf(3969.0f - 8.0f * (float)q)) * 0.5f);
  if (ii > 0 && pair_cum(ii) > q) --ii;   // fp rounding fixups
  if (pair_cum(ii + 1) <= q)     ++ii;
  i = ii;
  j = ii + 1 + (q - pair_cum(ii));
}

// (256,4): VGPR cap 128. (256,8) caused 30MB scratch spill (R1).
__global__ __launch_bounds__(256, 4) void magnet_fused(
    const float* __restrict__ x,      // [S,32,4]
    const float* __restrict__ L1W,    // [64,4]
    const float* __restrict__ L1b,    // [64]
    const float* __restrict__ L2W,    // [64,64]
    const float* __restrict__ L2b,    // [64]
    const float* __restrict__ I1W,    // [64,64]
    const float* __restrict__ I2W,    // [8,64]
    const float* __restrict__ I3,     // [992,2,4]
    const float* __restrict__ S1W,    // [4,4]
    const float* __restrict__ S1b,    // [4]
    const float* __restrict__ S2W,    // [32,2,2]
    const float* __restrict__ S2b,    // [32,2]
    float* __restrict__ out)          // [S,32,2]
{
  // Manual LDS layout (floats):
  //   [0,1152)      sAtp  [32][36] uint: h1 packed (k,k+1) pairs per n
  //   [1152,2304)   sBtp  [32][36] uint: h2 packed (k,k+1) pairs per n
  //   [0,1984)      pairval [496][4] (aliases sAtp+sBtp; live after phase 4a)
  //   [2304,4480)   sE    [32][68]  exp2(+g')
  //   [4480,6656)   sEm   [32][68]  exp2(-g')
  //   [6656,6912)   wpk   [32][8] uint: I2W packed (h,h+1) pairs per f
  //   [6912,7040)   sx    [32][4]
  //   [7040,7048)   sW    [8] row sums of I2W
  __shared__ __align__(16) float smem[7048];
  float* pairval = smem;                  // [496][4]
  unsigned* sAtp = (unsigned*)smem;       // [32][36]
  unsigned* sBtp = (unsigned*)(smem + 1152);
  float* sE  = smem + 2304;               // [32][68]
  float* sEm = smem + 4480;
  unsigned* wpk = (unsigned*)(smem + 6656);
  float* sx  = smem + 6912;
  float* sW  = smem + 7040;

  const int t = threadIdx.x;
  const int s = blockIdx.x;

  if (t < NOBJ * IN_F) sx[t] = x[s * (NOBJ * IN_F) + t];
  if (t < IFEAT) {                   // W[f] = sum_h I2W[f][h] (fp32)
    float a = 0.0f;
    const float4* w = (const float4*)(I2W + t * HID);
    #pragma unroll
    for (int c = 0; c < 16; ++c) { float4 v = w[c]; a += (v.x + v.y) + (v.z + v.w); }
    sW[t] = a;
  }
  {                                  // wpk[h2][f] = pack(I2W[f][2h2], I2W[f][2h2+1])
    const int f = t & 7, hh = t >> 3;
    h2 p = pack2(I2W[f * HID + 2 * hh], I2W[f * HID + 2 * hh + 1]);
    wpk[hh * 8 + f] = __builtin_bit_cast(unsigned, p);
  }
  __syncthreads();

  // ---- phase 1: h1 = relu(x @ L1W^T + L1b) -> sAtp[k2][n] (k-packed f16) ----
  {
    const int n = t & 31, kb = (t >> 5) * 8;
    const float x0 = sx[n * 4 + 0], x1 = sx[n * 4 + 1];
    const float x2 = sx[n * 4 + 2], x3 = sx[n * 4 + 3];
    float a[8];
    #pragma unroll
    for (int r = 0; r < 8; ++r) {
      const int k = kb + r;
      const float4 w = *(const float4*)(L1W + k * 4);
      float v = L1b[k];
      v = fmaf(x0, w.x, v); v = fmaf(x1, w.y, v);
      v = fmaf(x2, w.z, v); v = fmaf(x3, w.w, v);
      a[r] = fmaxf(v, 0.0f);
    }
    #pragma unroll
    for (int r2 = 0; r2 < 4; ++r2) {
      h2 p = pack2(a[2 * r2], a[2 * r2 + 1]);
      sAtp[((kb >> 1) + r2) * 36 + n] = __builtin_bit_cast(unsigned, p);
    }
  }
  __syncthreads();

  const int ro2 = t & 31;          // output row pair: rows 2*ro2, 2*ro2+1
  const int nb  = (t >> 5) * 4;    // 4 columns (objects)

  // ---- phase 2: h2 = relu(h1 @ L2W^T + L2b) -> sBtp[ho2][n] ----
  {
    const int ho = 2 * ro2;
    float acc0[4], acc1[4];
    const float b0 = L2b[ho], b1 = L2b[ho + 1];
    #pragma unroll
    for (int n = 0; n < 4; ++n) { acc0[n] = b0; acc1[n] = b1; }
    const float* w0 = L2W + ho * HID;
    const float* w1 = w0 + HID;
    #pragma unroll
    for (int k4 = 0; k4 < 16; ++k4) {
      const float4 wa = *(const float4*)(w0 + 4 * k4);
      const float4 wb = *(const float4*)(w1 + 4 * k4);
      const h2 wa01 = pack2(wa.x, wa.y), wa23 = pack2(wa.z, wa.w);
      const h2 wb01 = pack2(wb.x, wb.y), wb23 = pack2(wb.z, wb.w);
      const int4 r0 = *(const int4*)(sAtp + (2 * k4) * 36 + nb);
      const int4 r1 = *(const int4*)(sAtp + (2 * k4 + 1) * 36 + nb);
      const int* p0 = &r0.x; const int* p1 = &r1.x;
      #pragma unroll
      for (int n = 0; n < 4; ++n) {
        const h2 a0 = asb(p0[n]), a1 = asb(p1[n]);
        acc0[n] = fdot2f(wa01, a0, acc0[n]);
        acc0[n] = fdot2f(wa23, a1, acc0[n]);
        acc1[n] = fdot2f(wb01, a0, acc1[n]);
        acc1[n] = fdot2f(wb23, a1, acc1[n]);
      }
    }
    unsigned pk[4];
    #pragma unroll
    for (int n = 0; n < 4; ++n) {
      h2 p = pack2(fmaxf(acc0[n], 0.0f), fmaxf(acc1[n], 0.0f));
      pk[n] = __builtin_bit_cast(unsigned, p);
    }
    *(int4*)(sBtp + ro2 * 36 + nb) = *(int4*)pk;   // row=k-pair of phase 3
  }
  __syncthreads();

  // ---- phase 3: g = h2 @ I1W^T; store E=exp2(g'), Em=exp2(-g') (fp32) ----
  {
    const int go = 2 * ro2;
    float acc0[4] = {0.f,0.f,0.f,0.f}, acc1[4] = {0.f,0.f,0.f,0.f};
    const float* w0 = I1W + go * HID;
    const float* w1 = w0 + HID;
    #pragma unroll
    for (int k4 = 0; k4 < 16; ++k4) {
      const float4 wa = *(const float4*)(w0 + 4 * k4);
      const float4 wb = *(const float4*)(w1 + 4 * k4);
      const h2 wa01 = pack2(wa.x, wa.y), wa23 = pack2(wa.z, wa.w);
      const h2 wb01 = pack2(wb.x, wb.y), wb23 = pack2(wb.z, wb.w);
      const int4 r0 = *(const int4*)(sBtp + (2 * k4) * 36 + nb);
      const int4 r1 = *(const int4*)(sBtp + (2 * k4 + 1) * 36 + nb);
      const int* p0 = &r0.x; const int* p1 = &r1.x;
      #pragma unroll
      for (int n = 0; n < 4; ++n) {
        const h2 a0 = asb(p0[n]), a1 = asb(p1[n]);
        acc0[n] = fdot2f(wa01, a0, acc0[n]);
        acc0[n] = fdot2f(wa23, a1, acc0[n]);
        acc1[n] = fdot2f(wb01, a0, acc1[n]);
        acc1[n] = fdot2f(wb23, a1, acc1[n]);
      }
    }
    #pragma unroll
    for (int n = 0; n < 4; ++n) {
      const int no = nb + n;
      float g0 = fminf(fmaxf(acc0[n] * TWO_LOG2E, -60.0f), 60.0f);
      float g1 = fminf(fmaxf(acc1[n] * TWO_LOG2E, -60.0f), 60.0f);
      sE [no * 68 + go]     = EXP2F(g0);
      sEm[no * 68 + go]     = EXP2F(-g0);
      sE [no * 68 + go + 1] = EXP2F(g1);
      sEm[no * 68 + go + 1] = EXP2F(-g1);
    }
  }
  __syncthreads();

  // ---- phase 4a: 2 pairs/thread; th = 1-2*rcp(Ei*Emj+1); u = W - 2*sum(w*r)
  // dot over h via packed f16 fdot2; results -> pairval (no atomics).
  {
    int i1, j1, i2, j2;
    pair_decode(t, i1, j1);
    const bool has2 = (t + 256) < NPAIR_HALF;
    pair_decode(has2 ? t + 256 : 0, i2, j2);

    float sWr[IFEAT];
    #pragma unroll
    for (int f = 0; f < IFEAT; ++f) sWr[f] = sW[f];

    float da[IFEAT] = {0.f,0.f,0.f,0.f,0.f,0.f,0.f,0.f};
    float db[IFEAT] = {0.f,0.f,0.f,0.f,0.f,0.f,0.f,0.f};
    const float4* Ei1 = (const float4*)(sE  + i1 * 68);
    const float4* Mj1 = (const float4*)(sEm + j1 * 68);
    const float4* Ei2 = (const float4*)(sE  + i2 * 68);
    const float4* Mj2 = (const float4*)(sEm + j2 * 68);

    #pragma unroll 4
    for (int hb = 0; hb < 16; ++hb) {      // 4 h per iter
      const float4 a1 = Ei1[hb], b1 = Mj1[hb];
      const float4 a2 = Ei2[hb], b2 = Mj2[hb];
      float r1[4], r2[4];
      #pragma unroll
      for (int c = 0; c < 4; ++c) {
        r1[c] = __builtin_amdgcn_rcpf(fmaf((&a1.x)[c], (&b1.x)[c], 1.0f));
        r2[c] = __builtin_amdgcn_rcpf(fmaf((&a2.x)[c], (&b2.x)[c], 1.0f));
      }
      const h2 p1a = pack2(r1[0], r1[1]), p1b = pack2(r1[2], r1[3]);
      const h2 p2a = pack2(r2[0], r2[1]), p2b = pack2(r2[2], r2[3]);
      const int4 w0 = *(const int4*)(wpk + (2 * hb) * 8);       // f 0..3, h2=2hb
      const int4 w1 = *(const int4*)(wpk + (2 * hb) * 8 + 4);   // f 4..7
      const int4 w2 = *(const int4*)(wpk + (2 * hb + 1) * 8);
      const int4 w3 = *(const int4*)(wpk + (2 * hb + 1) * 8 + 4);
      const int* q0 = &w0.x; const int* q1 = &w1.x;
      const int* q2 = &w2.x; const int* q3 = &w3.x;
      #pragma unroll
      for (int f = 0; f < 4; ++f) {
        da[f]     = fdot2f(asb(q0[f]), p1a, da[f]);
        da[f]     = fdot2f(asb(q2[f]), p1b, da[f]);
        da[4 + f] = fdot2f(asb(q1[f]), p1a, da[4 + f]);
        da[4 + f] = fdot2f(asb(q3[f]), p1b, da[4 + f]);
        db[f]     = fdot2f(asb(q0[f]), p2a, db[f]);
        db[f]     = fdot2f(asb(q2[f]), p2b, db[f]);
        db[4 + f] = fdot2f(asb(q1[f]), p2a, db[4 + f]);
        db[4 + f] = fdot2f(asb(q3[f]), p2b, db[4 + f]);
      }
    }
    __syncthreads();   // pairval aliases sAtp/sBtp (dead); also covers sE reads

    {
      const float* cij = I3 + (i1 * 31 + (j1 - 1)) * 8;
      const float* cji = I3 + (j1 * 31 + i1) * 8;
      float vi0 = 0.f, vi1 = 0.f, vj0 = 0.f, vj1 = 0.f;
      #pragma unroll
      for (int k = 0; k < 4; ++k) {
        const float v = tanh_u(fmaf(-2.0f, da[k], sWr[k]));
        vi0 = fmaf(cij[k],  v, vi0);
        vj0 = fmaf(cji[k], -v, vj0);
      }
      #pragma unroll
      for (int k = 0; k < 4; ++k) {
        const float v = tanh_u(fmaf(-2.0f, da[4 + k], sWr[4 + k]));
        vi1 = fmaf(cij[4 + k],  v, vi1);
        vj1 = fmaf(cji[4 + k], -v, vj1);
      }
      float4 pv; pv.x = vi0; pv.y = vi1; pv.z = vj0; pv.w = vj1;
      *(float4*)(pairval + t * 4) = pv;
    }
    if (has2) {
      const float* cij = I3 + (i2 * 31 + (j2 - 1)) * 8;
      const float* cji = I3 + (j2 * 31 + i2) * 8;
      float vi0 = 0.f, vi1 = 0.f, vj0 = 0.f, vj1 = 0.f;
      #pragma unroll
      for (int k = 0; k < 4; ++k) {
        const float v = tanh_u(fmaf(-2.0f, db[k], sWr[k]));
        vi0 = fmaf(cij[k],  v, vi0);
        vj0 = fmaf(cji[k], -v, vj0);
      }
      #pragma unroll
      for (int k = 0; k < 4; ++k) {
        const float v = tanh_u(fmaf(-2.0f, db[4 + k], sWr[4 + k]));
        vi1 = fmaf(cij[4 + k],  v, vi1);
        vj1 = fmaf(cji[4 + k], -v, vj1);
      }
      float4 pv; pv.x = vi0; pv.y = vi1; pv.z = vj0; pv.w = vj1;
      *(float4*)(pairval + (t + 256) * 4) = pv;
    }
  }
  __syncthreads();

  // ---- phase 4b + epilogue: row-gather reduction (no atomics) ----
  if (t < 64) {
    const int i = t >> 1, d = t & 1;
    float sum = 0.0f;
    for (int j = 0; j < i; ++j)                    // pair (j,i), vj slot
      sum += pairval[(pair_cum(j) + (i - j - 1)) * 4 + 2 + d];
    const int base = pair_cum(i);
    for (int m = 0; m < 31 - i; ++m)               // pair (i,*), vi slot
      sum += pairval[(base + m) * 4 + d];

    float res = S2b[t] + sum;
    #pragma unroll
    for (int k = 0; k < 2; ++k) {
      const int f = d * 2 + k;
      float hs = S1b[f];
      hs = fmaf(sx[i * 4 + 0], S1W[f * 4 + 0], hs);
      hs = fmaf(sx[i * 4 + 1], S1W[f * 4 + 1], hs);
      hs = fmaf(sx[i * 4 + 2], S1W[f * 4 + 2], hs);
      hs = fmaf(sx[i * 4 + 3], S1W[f * 4 + 3], hs);
      hs = fmaxf(hs, 0.0f);
      res = fmaf(hs, S2W[i * 4 + d * 2 + k], res);
    }
    out[s * (NOBJ * 2) + t] = res;
  }
}

extern "C" void kernel_launch(void* const* d_in, const int* in_sizes, int n_in,
                              void* d_out, int out_size, void* d_ws, size_t ws_size,
                              hipStream_t stream) {
  const float* x   = (const float*)d_in[0];
  const float* L1W = (const float*)d_in[1];
  const float* L1b = (const float*)d_in[2];
  const float* L2W = (const float*)d_in[3];
  const float* L2b = (const float*)d_in[4];
  const float* I1W = (const float*)d_in[5];
  const float* I2W = (const float*)d_in[6];
  const float* I3  = (const float*)d_in[7];
  const float* S1W = (const float*)d_in[8];
  const float* S1b = (const float*)d_in[9];
  const float* S2W = (const float*)d_in[10];
  const float* S2b = (const float*)d_in[11];
  float* outp = (float*)d_out;

  magnet_fused<<<SEQ, 256, 0, stream>>>(x, L1W, L1b, L2W, L2b, I1W, I2W, I3,
                                        S1W, S1b, S2W, S2b, outp);
}

// Round 8
// 130.079 us; speedup vs baseline: 1.6093x; 1.6093x over previous
//
#include <hip/hip_runtime.h>
#include <math.h>

#define SEQ   4096
#define NOBJ  32
#define IN_F  4
#define HID   64
#define IFEAT 8
#define NPAIR_HALF 496   // 32*31/2 unordered pairs

#define TWO_LOG2E 2.8853900817779268f   // 2*log2(e)

#if __has_builtin(__builtin_amdgcn_exp2f)
  #define EXP2F(x) __builtin_amdgcn_exp2f(x)
#else
  #define EXP2F(x) exp2f(x)
#endif

typedef _Float16 h2    __attribute__((ext_vector_type(2)));
typedef _Float16 f16x8 __attribute__((ext_vector_type(8)));
typedef float    f32x4 __attribute__((ext_vector_type(4)));

__device__ __forceinline__ h2 pack2(float a, float b) {
  return __builtin_bit_cast(h2, __builtin_amdgcn_cvt_pkrtz(a, b));
}
__device__ __forceinline__ unsigned pbits(h2 v) { return __builtin_bit_cast(unsigned, v); }

// 8 floats -> f16x8 fragment (k ascending)
__device__ __forceinline__ f16x8 pack8(float4 a, float4 b) {
  int4 v;
  v.x = (int)pbits(pack2(a.x, a.y));
  v.y = (int)pbits(pack2(a.z, a.w));
  v.z = (int)pbits(pack2(b.x, b.y));
  v.w = (int)pbits(pack2(b.z, b.w));
  return __builtin_bit_cast(f16x8, v);
}

// tanh via exp2: tanh(x) = 1 - 2/(exp2(x*2log2e)+1)
__device__ __forceinline__ float tanh_u(float x) {
  float e = EXP2F(x * TWO_LOG2E);
  float r = __builtin_amdgcn_rcpf(e + 1.0f);
  return fmaf(-2.0f, r, 1.0f);
}

// cumulative pair count before row i (i<j ordering): C(i) = i*(63-i)/2
__device__ __forceinline__ int pair_cum(int i) { return (i * (63 - i)) >> 1; }

__device__ __forceinline__ void pair_decode(int q, int& i, int& j) {
  int ii = (int)((63.0f - sqrtf(3969.0f - 8.0f * (float)q)) * 0.5f);
  if (ii > 0 && pair_cum(ii) > q) --ii;   // fp rounding fixups
  if (pair_cum(ii + 1) <= q)     ++ii;
  i = ii;
  j = ii + 1 + (q - pair_cum(ii));
}

// (256,4): VGPR cap 128. (256,8) caused 30MB scratch spill (R1).
__global__ __launch_bounds__(256, 4) void magnet_fused(
    const float* __restrict__ x,      // [S,32,4]
    const float* __restrict__ L1W,    // [64,4]
    const float* __restrict__ L1b,    // [64]
    const float* __restrict__ L2W,    // [64,64]
    const float* __restrict__ L2b,    // [64]
    const float* __restrict__ I1W,    // [64,64]
    const float* __restrict__ I2W,    // [8,64]
    const float* __restrict__ I3,     // [992,2,4]
    const float* __restrict__ S1W,    // [4,4]
    const float* __restrict__ S1b,    // [4]
    const float* __restrict__ S2W,    // [32,2,2]
    const float* __restrict__ S2b,    // [32,2]
    float* __restrict__ out)          // [S,32,2]
{
  // LDS layout (float units):
  //   [0,1152)     sAtp [32][36] uint: h1 f16-pairs, [n][k2] (B-frag layout)
  //   [1152,2304)  sBtp [32][36] uint: h2 f16-pairs, [n][k2]
  //   [0,1984)     pairval [496][4]  (aliases sAtp+sBtp, live after phase 4a)
  //   [2304,4480)  sE  [32][68] fp32 exp2(+g')
  //   [4480,6656)  sEm [32][68] fp32 exp2(-g')
  //   [6656,6688)  sx  [32][4... actually 32 floats? no: 32*4=128]
  __shared__ __align__(16) float smem[6824];
  unsigned* sAtp   = (unsigned*)smem;          // [32][36]
  unsigned* sBtp   = (unsigned*)(smem + 1152); // [32][36]
  float*    pairval = smem;                    // [496][4]
  float*    sE  = smem + 2304;                 // [32][68]
  float*    sEm = smem + 4480;                 // [32][68]
  float*    sx  = smem + 6656;                 // [32][4] -> 6656..6784
  float*    sW  = smem + 6784;                 // [8]     -> 6784..6792

  const int t = threadIdx.x;
  const int s = blockIdx.x;

  if (t < NOBJ * IN_F) sx[t] = x[s * (NOBJ * IN_F) + t];
  if (t < IFEAT) {                   // W[f] = sum_h I2W[f][h] (fp32)
    float a = 0.0f;
    const float4* w = (const float4*)(I2W + t * HID);
    #pragma unroll
    for (int c = 0; c < 16; ++c) { float4 v = w[c]; a += (v.x + v.y) + (v.z + v.w); }
    sW[t] = a;
  }
  __syncthreads();

  // ---- phase 1: h1 = relu(x @ L1W^T + L1b) fp32, pack f16 -> sAtp[n][k2] ----
  {
    const int n = t & 31, gI = t >> 5, kb = gI * 8;
    const float x0 = sx[n * 4 + 0], x1 = sx[n * 4 + 1];
    const float x2 = sx[n * 4 + 2], x3 = sx[n * 4 + 3];
    float a[8];
    #pragma unroll
    for (int r = 0; r < 8; ++r) {
      const int k = kb + r;
      const float4 w = *(const float4*)(L1W + k * 4);
      float v = L1b[k];
      v = fmaf(x0, w.x, v); v = fmaf(x1, w.y, v);
      v = fmaf(x2, w.z, v); v = fmaf(x3, w.w, v);
      a[r] = fmaxf(v, 0.0f);
    }
    int4 pk;
    pk.x = (int)pbits(pack2(a[0], a[1]));
    pk.y = (int)pbits(pack2(a[2], a[3]));
    pk.z = (int)pbits(pack2(a[4], a[5]));
    pk.w = (int)pbits(pack2(a[6], a[7]));
    *(int4*)(sAtp + n * 36 + gI * 4) = pk;
  }
  __syncthreads();

  const int lane = t & 63;
  const int wv   = t >> 6;        // wave id 0..3 = M-tile (16 output feats)
  const int qd   = lane >> 4;     // quad 0..3
  const int ln   = lane & 15;

  // ---- phase 2: h2 = relu(h1 @ L2W^T + L2b) via MFMA -> sBtp[n][k2] ----
  // D[m][n] = sum_k L2W[m][k] * h1[n][k];  A[m=ln][k=qd*8+j], B[k=qd*8+j][n=ln]
  {
    const int m = 16 * wv + ln;
    const float* wr = L2W + m * HID;
    const f16x8 A0 = pack8(*(const float4*)(wr + 8 * qd),
                           *(const float4*)(wr + 8 * qd + 4));
    const f16x8 A1 = pack8(*(const float4*)(wr + 32 + 8 * qd),
                           *(const float4*)(wr + 32 + 8 * qd + 4));
    const float4 bias = *(const float4*)(L2b + 16 * wv + 4 * qd);  // m=4qd+reg
    #pragma unroll
    for (int nt = 0; nt < 2; ++nt) {
      const int n = nt * 16 + ln;
      const f16x8 B0 = __builtin_bit_cast(f16x8, *(const int4*)(sAtp + n * 36 + 4 * qd));
      const f16x8 B1 = __builtin_bit_cast(f16x8, *(const int4*)(sAtp + n * 36 + 16 + 4 * qd));
      f32x4 c; c[0] = bias.x; c[1] = bias.y; c[2] = bias.z; c[3] = bias.w;
      c = __builtin_amdgcn_mfma_f32_16x16x32_f16(A0, B0, c, 0, 0, 0);
      c = __builtin_amdgcn_mfma_f32_16x16x32_f16(A1, B1, c, 0, 0, 0);
      // lane holds D[m=16wv+4qd+reg][n]; pack m-pairs -> k2 = 8wv+2qd+{0,1}
      sBtp[n * 36 + 8 * wv + 2 * qd]     = pbits(pack2(fmaxf(c[0], 0.f), fmaxf(c[1], 0.f)));
      sBtp[n * 36 + 8 * wv + 2 * qd + 1] = pbits(pack2(fmaxf(c[2], 0.f), fmaxf(c[3], 0.f)));
    }
  }
  __syncthreads();

  // ---- phase 3: g = h2 @ I1W^T via MFMA; store E=exp2(g'), Em=exp2(-g') ----
  {
    const int m = 16 * wv + ln;
    const float* wr = I1W + m * HID;
    const f16x8 A0 = pack8(*(const float4*)(wr + 8 * qd),
                           *(const float4*)(wr + 8 * qd + 4));
    const f16x8 A1 = pack8(*(const float4*)(wr + 32 + 8 * qd),
                           *(const float4*)(wr + 32 + 8 * qd + 4));
    #pragma unroll
    for (int nt = 0; nt < 2; ++nt) {
      const int n = nt * 16 + ln;
      const f16x8 B0 = __builtin_bit_cast(f16x8, *(const int4*)(sBtp + n * 36 + 4 * qd));
      const f16x8 B1 = __builtin_bit_cast(f16x8, *(const int4*)(sBtp + n * 36 + 16 + 4 * qd));
      f32x4 c; c[0] = 0.f; c[1] = 0.f; c[2] = 0.f; c[3] = 0.f;
      c = __builtin_amdgcn_mfma_f32_16x16x32_f16(A0, B0, c, 0, 0, 0);
      c = __builtin_amdgcn_mfma_f32_16x16x32_f16(A1, B1, c, 0, 0, 0);
      #pragma unroll
      for (int r = 0; r < 4; ++r) {
        const int mo = 16 * wv + 4 * qd + r;
        float gp = fminf(fmaxf(c[r] * TWO_LOG2E, -60.0f), 60.0f);
        sE [n * 68 + mo] = EXP2F(gp);
        sEm[n * 68 + mo] = EXP2F(-gp);
      }
    }
  }
  __syncthreads();

  // ---- phase 4a (R4-proven): 2 pairs/thread; th = 1-2*rcp(Ei*Emj+1);
  // u = W - 2*sum_h(w*r); I2W via lane-uniform global (s_load). ----
  {
    int i1, j1, i2, j2;
    pair_decode(t, i1, j1);
    const bool has2 = (t + 256) < NPAIR_HALF;
    pair_decode(has2 ? t + 256 : 0, i2, j2);

    float sWr[IFEAT];
    #pragma unroll
    for (int f = 0; f < IFEAT; ++f) sWr[f] = sW[f];

    float da[IFEAT] = {0.f,0.f,0.f,0.f,0.f,0.f,0.f,0.f};
    float db[IFEAT] = {0.f,0.f,0.f,0.f,0.f,0.f,0.f,0.f};
    const float4* Ei1 = (const float4*)(sE  + i1 * 68);
    const float4* Mj1 = (const float4*)(sEm + j1 * 68);
    const float4* Ei2 = (const float4*)(sE  + i2 * 68);
    const float4* Mj2 = (const float4*)(sEm + j2 * 68);

    #pragma unroll 4
    for (int hb = 0; hb < 16; ++hb) {
      const float4 a1 = Ei1[hb], b1 = Mj1[hb];
      const float4 a2 = Ei2[hb], b2 = Mj2[hb];
      float r1[4], r2[4];
      #pragma unroll
      for (int c = 0; c < 4; ++c) {
        r1[c] = __builtin_amdgcn_rcpf(fmaf((&a1.x)[c], (&b1.x)[c], 1.0f));
        r2[c] = __builtin_amdgcn_rcpf(fmaf((&a2.x)[c], (&b2.x)[c], 1.0f));
      }
      #pragma unroll
      for (int f = 0; f < IFEAT; ++f) {
        const float4 w = *(const float4*)(I2W + f * HID + hb * 4); // uniform->s_load
        da[f] = fmaf(w.x, r1[0], da[f]); da[f] = fmaf(w.y, r1[1], da[f]);
        da[f] = fmaf(w.z, r1[2], da[f]); da[f] = fmaf(w.w, r1[3], da[f]);
        db[f] = fmaf(w.x, r2[0], db[f]); db[f] = fmaf(w.y, r2[1], db[f]);
        db[f] = fmaf(w.z, r2[2], db[f]); db[f] = fmaf(w.w, r2[3], db[f]);
      }
    }

    {
      const float* cij = I3 + (i1 * 31 + (j1 - 1)) * 8;
      const float* cji = I3 + (j1 * 31 + i1) * 8;
      float vi0 = 0.f, vi1 = 0.f, vj0 = 0.f, vj1 = 0.f;
      #pragma unroll
      for (int k = 0; k < 4; ++k) {
        const float v = tanh_u(fmaf(-2.0f, da[k], sWr[k]));
        vi0 = fmaf(cij[k],  v, vi0);
        vj0 = fmaf(cji[k], -v, vj0);
      }
      #pragma unroll
      for (int k = 0; k < 4; ++k) {
        const float v = tanh_u(fmaf(-2.0f, da[4 + k], sWr[4 + k]));
        vi1 = fmaf(cij[4 + k],  v, vi1);
        vj1 = fmaf(cji[4 + k], -v, vj1);
      }
      float4 pv; pv.x = vi0; pv.y = vi1; pv.z = vj0; pv.w = vj1;
      *(float4*)(pairval + t * 4) = pv;
    }
    if (has2) {
      const float* cij = I3 + (i2 * 31 + (j2 - 1)) * 8;
      const float* cji = I3 + (j2 * 31 + i2) * 8;
      float vi0 = 0.f, vi1 = 0.f, vj0 = 0.f, vj1 = 0.f;
      #pragma unroll
      for (int k = 0; k < 4; ++k) {
        const float v = tanh_u(fmaf(-2.0f, db[k], sWr[k]));
        vi0 = fmaf(cij[k],  v, vi0);
        vj0 = fmaf(cji[k], -v, vj0);
      }
      #pragma unroll
      for (int k = 0; k < 4; ++k) {
        const float v = tanh_u(fmaf(-2.0f, db[4 + k], sWr[4 + k]));
        vi1 = fmaf(cij[4 + k],  v, vi1);
        vj1 = fmaf(cji[4 + k], -v, vj1);
      }
      float4 pv; pv.x = vi0; pv.y = vi1; pv.z = vj0; pv.w = vj1;
      *(float4*)(pairval + (t + 256) * 4) = pv;
    }
  }
  __syncthreads();

  // ---- phase 4b + epilogue: row-gather reduction (no atomics) ----
  if (t < 64) {
    const int i = t >> 1, d = t & 1;
    float sum = 0.0f;
    for (int j = 0; j < i; ++j)                    // pair (j,i), vj slot
      sum += pairval[(pair_cum(j) + (i - j - 1)) * 4 + 2 + d];
    const int base = pair_cum(i);
    for (int m = 0; m < 31 - i; ++m)               // pair (i,*), vi slot
      sum += pairval[(base + m) * 4 + d];

    float res = S2b[t] + sum;
    #pragma unroll
    for (int k = 0; k < 2; ++k) {
      const int f = d * 2 + k;
      float hs = S1b[f];
      hs = fmaf(sx[i * 4 + 0], S1W[f * 4 + 0], hs);
      hs = fmaf(sx[i * 4 + 1], S1W[f * 4 + 1], hs);
      hs = fmaf(sx[i * 4 + 2], S1W[f * 4 + 2], hs);
      hs = fmaf(sx[i * 4 + 3], S1W[f * 4 + 3], hs);
      hs = fmaxf(hs, 0.0f);
      res = fmaf(hs, S2W[i * 4 + d * 2 + k], res);
    }
    out[s * (NOBJ * 2) + t] = res;
  }
}

extern "C" void kernel_launch(void* const* d_in, const int* in_sizes, int n_in,
                              void* d_out, int out_size, void* d_ws, size_t ws_size,
                              hipStream_t stream) {
  const float* x   = (const float*)d_in[0];
  const float* L1W = (const float*)d_in[1];
  const float* L1b = (const float*)d_in[2];
  const float* L2W = (const float*)d_in[3];
  const float* L2b = (const float*)d_in[4];
  const float* I1W = (const float*)d_in[5];
  const float* I2W = (const float*)d_in[6];
  const float* I3  = (const float*)d_in[7];
  const float* S1W = (const float*)d_in[8];
  const float* S1b = (const float*)d_in[9];
  const float* S2W = (const float*)d_in[10];
  const float* S2b = (const float*)d_in[11];
  float* outp = (float*)d_out;

  magnet_fused<<<SEQ, 256, 0, stream>>>(x, L1W, L1b, L2W, L2b, I1W, I2W, I3,
                                        S1W, S1b, S2W, S2b, outp);
}

// Round 9
// 124.082 us; speedup vs baseline: 1.6871x; 1.0483x over previous
//
#include <hip/hip_runtime.h>
#include <math.h>

#define SEQ   4096
#define NOBJ  32
#define IN_F  4
#define HID   64
#define IFEAT 8
#define NPAIR_HALF 496   // 32*31/2 unordered pairs; = 31 tiles * 16
#define NTILE 31

#define TWO_LOG2E 2.8853900817779268f   // 2*log2(e)

#if __has_builtin(__builtin_amdgcn_exp2f)
  #define EXP2F(x) __builtin_amdgcn_exp2f(x)
#else
  #define EXP2F(x) exp2f(x)
#endif

typedef _Float16 h2    __attribute__((ext_vector_type(2)));
typedef _Float16 f16x8 __attribute__((ext_vector_type(8)));
typedef float    f32x4 __attribute__((ext_vector_type(4)));

__device__ __forceinline__ h2 pack2(float a, float b) {
  return __builtin_bit_cast(h2, __builtin_amdgcn_cvt_pkrtz(a, b));
}
__device__ __forceinline__ unsigned pbits(h2 v) { return __builtin_bit_cast(unsigned, v); }

__device__ __forceinline__ f16x8 pack8(float4 a, float4 b) {
  int4 v;
  v.x = (int)pbits(pack2(a.x, a.y));
  v.y = (int)pbits(pack2(a.z, a.w));
  v.z = (int)pbits(pack2(b.x, b.y));
  v.w = (int)pbits(pack2(b.z, b.w));
  return __builtin_bit_cast(f16x8, v);
}

__device__ __forceinline__ f16x8 pack8f(const float* r) {
  int4 v;
  v.x = (int)pbits(pack2(r[0], r[1]));
  v.y = (int)pbits(pack2(r[2], r[3]));
  v.z = (int)pbits(pack2(r[4], r[5]));
  v.w = (int)pbits(pack2(r[6], r[7]));
  return __builtin_bit_cast(f16x8, v);
}

// tanh via exp2: tanh(x) = 1 - 2/(exp2(x*2log2e)+1)
__device__ __forceinline__ float tanh_u(float x) {
  float e = EXP2F(x * TWO_LOG2E);
  float r = __builtin_amdgcn_rcpf(e + 1.0f);
  return fmaf(-2.0f, r, 1.0f);
}

// cumulative pair count before row i (i<j ordering): C(i) = i*(63-i)/2
__device__ __forceinline__ int pair_cum(int i) { return (i * (63 - i)) >> 1; }

__device__ __forceinline__ void pair_decode(int q, int& i, int& j) {
  int ii = (int)((63.0f - sqrtf(3969.0f - 8.0f * (float)q)) * 0.5f);
  if (ii > 0 && pair_cum(ii) > q) --ii;   // fp rounding fixups
  if (pair_cum(ii + 1) <= q)     ++ii;
  i = ii;
  j = ii + 1 + (q - pair_cum(ii));
}

// (256,4): VGPR cap 128. (256,8) caused 30MB scratch spill (R1).
__global__ __launch_bounds__(256, 4) void magnet_fused(
    const float* __restrict__ x,      // [S,32,4]
    const float* __restrict__ L1W,    // [64,4]
    const float* __restrict__ L1b,    // [64]
    const float* __restrict__ L2W,    // [64,64]
    const float* __restrict__ L2b,    // [64]
    const float* __restrict__ I1W,    // [64,64]
    const float* __restrict__ I2W,    // [8,64]
    const float* __restrict__ I3,     // [992,2,4]
    const float* __restrict__ S1W,    // [4,4]
    const float* __restrict__ S1b,    // [4]
    const float* __restrict__ S2W,    // [32,2,2]
    const float* __restrict__ S2b,    // [32,2]
    float* __restrict__ out)          // [S,32,2]
{
  // LDS layout (float units):
  //   [0,1152)     sAtp [32][36] uint: h1 f16-pairs [n][k2]  (phases 1-2)
  //   [1152,2304)  sBtp [32][36] uint: h2 f16-pairs [n][k2]  (phases 2-3)
  //   [0,1984)     sv   [496][8] f16: tanh values  (phase 4a->4b, aliases)
  //   [2304,4480)  sE   [32][68] fp32 exp2(+g')
  //   [4480,6656)  sEm  [32][68] fp32 exp2(-g')
  //   [6656,7168)  wB   [16][32] uint: I2W f16-pairs B-frag layout [n][k2]
  //   [7168,7296)  sx   [32][4]
  //   [7296,7304)  sW   [8] row sums of I2W
  //   [7304,7560)  part [256] phase-4b partials
  __shared__ __align__(16) float smem[7560];
  unsigned*  sAtp = (unsigned*)smem;           // [32][36]
  unsigned*  sBtp = (unsigned*)(smem + 1152);  // [32][36]
  _Float16*  sv   = (_Float16*)smem;           // [496][8]
  float*     sE   = smem + 2304;               // [32][68]
  float*     sEm  = smem + 4480;               // [32][68]
  unsigned*  wB   = (unsigned*)(smem + 6656);  // [16][32]
  float*     sx   = smem + 7168;               // [32][4]
  float*     sW   = smem + 7296;               // [8]
  float*     part = smem + 7304;               // [256]

  const int t = threadIdx.x;
  const int s = blockIdx.x;

  if (t < NOBJ * IN_F) sx[t] = x[s * (NOBJ * IN_F) + t];
  if (t < IFEAT) {                   // W[f] = sum_h I2W[f][h] (fp32)
    float a = 0.0f;
    const float4* w = (const float4*)(I2W + t * HID);
    #pragma unroll
    for (int c = 0; c < 16; ++c) { float4 v = w[c]; a += (v.x + v.y) + (v.z + v.w); }
    sW[t] = a;
  }
  #pragma unroll
  for (int idx = t; idx < 512; idx += 256) {   // wB[n][k2]; rows 8-15 zero
    const int n = idx >> 5, k2 = idx & 31;
    wB[idx] = (n < IFEAT)
      ? pbits(pack2(I2W[n * HID + 2 * k2], I2W[n * HID + 2 * k2 + 1])) : 0u;
  }
  __syncthreads();

  // ---- phase 1: h1 = relu(x @ L1W^T + L1b) fp32, pack f16 -> sAtp[n][k2] ----
  {
    const int n = t & 31, gI = t >> 5, kb = gI * 8;
    const float x0 = sx[n * 4 + 0], x1 = sx[n * 4 + 1];
    const float x2 = sx[n * 4 + 2], x3 = sx[n * 4 + 3];
    float a[8];
    #pragma unroll
    for (int r = 0; r < 8; ++r) {
      const int k = kb + r;
      const float4 w = *(const float4*)(L1W + k * 4);
      float v = L1b[k];
      v = fmaf(x0, w.x, v); v = fmaf(x1, w.y, v);
      v = fmaf(x2, w.z, v); v = fmaf(x3, w.w, v);
      a[r] = fmaxf(v, 0.0f);
    }
    int4 pk;
    pk.x = (int)pbits(pack2(a[0], a[1]));
    pk.y = (int)pbits(pack2(a[2], a[3]));
    pk.z = (int)pbits(pack2(a[4], a[5]));
    pk.w = (int)pbits(pack2(a[6], a[7]));
    *(int4*)(sAtp + n * 36 + gI * 4) = pk;
  }
  __syncthreads();

  const int lane = t & 63;
  const int wv   = t >> 6;        // wave id
  const int qd   = lane >> 4;     // quad 0..3
  const int ln   = lane & 15;

  // ---- phase 2: h2 = relu(h1 @ L2W^T + L2b) via MFMA -> sBtp[n][k2] ----
  {
    const int m = 16 * wv + ln;
    const float* wr = L2W + m * HID;
    const f16x8 A0 = pack8(*(const float4*)(wr + 8 * qd),
                           *(const float4*)(wr + 8 * qd + 4));
    const f16x8 A1 = pack8(*(const float4*)(wr + 32 + 8 * qd),
                           *(const float4*)(wr + 32 + 8 * qd + 4));
    const float4 bias = *(const float4*)(L2b + 16 * wv + 4 * qd);
    #pragma unroll
    for (int nt = 0; nt < 2; ++nt) {
      const int n = nt * 16 + ln;
      const f16x8 B0 = __builtin_bit_cast(f16x8, *(const int4*)(sAtp + n * 36 + 4 * qd));
      const f16x8 B1 = __builtin_bit_cast(f16x8, *(const int4*)(sAtp + n * 36 + 16 + 4 * qd));
      f32x4 c; c[0] = bias.x; c[1] = bias.y; c[2] = bias.z; c[3] = bias.w;
      c = __builtin_amdgcn_mfma_f32_16x16x32_f16(A0, B0, c, 0, 0, 0);
      c = __builtin_amdgcn_mfma_f32_16x16x32_f16(A1, B1, c, 0, 0, 0);
      sBtp[n * 36 + 8 * wv + 2 * qd]     = pbits(pack2(fmaxf(c[0], 0.f), fmaxf(c[1], 0.f)));
      sBtp[n * 36 + 8 * wv + 2 * qd + 1] = pbits(pack2(fmaxf(c[2], 0.f), fmaxf(c[3], 0.f)));
    }
  }
  __syncthreads();

  // ---- phase 3: g = h2 @ I1W^T via MFMA; store E=exp2(g'), Em=exp2(-g') ----
  {
    const int m = 16 * wv + ln;
    const float* wr = I1W + m * HID;
    const f16x8 A0 = pack8(*(const float4*)(wr + 8 * qd),
                           *(const float4*)(wr + 8 * qd + 4));
    const f16x8 A1 = pack8(*(const float4*)(wr + 32 + 8 * qd),
                           *(const float4*)(wr + 32 + 8 * qd + 4));
    #pragma unroll
    for (int nt = 0; nt < 2; ++nt) {
      const int n = nt * 16 + ln;
      const f16x8 B0 = __builtin_bit_cast(f16x8, *(const int4*)(sBtp + n * 36 + 4 * qd));
      const f16x8 B1 = __builtin_bit_cast(f16x8, *(const int4*)(sBtp + n * 36 + 16 + 4 * qd));
      f32x4 c; c[0] = 0.f; c[1] = 0.f; c[2] = 0.f; c[3] = 0.f;
      c = __builtin_amdgcn_mfma_f32_16x16x32_f16(A0, B0, c, 0, 0, 0);
      c = __builtin_amdgcn_mfma_f32_16x16x32_f16(A1, B1, c, 0, 0, 0);
      #pragma unroll
      for (int r = 0; r < 4; ++r) {
        const int mo = 16 * wv + 4 * qd + r;
        float gp = fminf(fmaxf(c[r] * TWO_LOG2E, -60.0f), 60.0f);
        sE [n * 68 + mo] = EXP2F(gp);
        sEm[n * 68 + mo] = EXP2F(-gp);
      }
    }
  }
  __syncthreads();

  // ---- phase 4a: pair dots via MFMA. Tile = 16 pairs; A[m=pair][k=h] = r
  // values (f16), B[k=h][n=f] = I2W (f16, from wB). r = rcp(Ei*Emj+1).
  // u[p][f] = W[f] - 2*c;  v = tanh(u) -> sv[p][f] (f16), lanes ln<8. ----
  {
    const f16x8 B0 = __builtin_bit_cast(f16x8, *(const int4*)(wB + ln * 32 + 4 * qd));
    const f16x8 B1 = __builtin_bit_cast(f16x8, *(const int4*)(wB + ln * 32 + 16 + 4 * qd));
    const float Wf = sW[ln & 7];

    for (int tile = wv; tile < NTILE; tile += 4) {
      int i, j;
      pair_decode(tile * 16 + ln, i, j);
      const float* Ei = sE  + i * 68 + qd * 8;
      const float* Mj = sEm + j * 68 + qd * 8;
      const float4 e0 = *(const float4*)(Ei);
      const float4 e1 = *(const float4*)(Ei + 4);
      const float4 e2 = *(const float4*)(Ei + 32);
      const float4 e3 = *(const float4*)(Ei + 36);
      const float4 m0 = *(const float4*)(Mj);
      const float4 m1 = *(const float4*)(Mj + 4);
      const float4 m2 = *(const float4*)(Mj + 32);
      const float4 m3 = *(const float4*)(Mj + 36);
      float r0[8], r1[8];
      #pragma unroll
      for (int c = 0; c < 4; ++c) {
        r0[c]     = __builtin_amdgcn_rcpf(fmaf((&e0.x)[c], (&m0.x)[c], 1.0f));
        r0[4 + c] = __builtin_amdgcn_rcpf(fmaf((&e1.x)[c], (&m1.x)[c], 1.0f));
        r1[c]     = __builtin_amdgcn_rcpf(fmaf((&e2.x)[c], (&m2.x)[c], 1.0f));
        r1[4 + c] = __builtin_amdgcn_rcpf(fmaf((&e3.x)[c], (&m3.x)[c], 1.0f));
      }
      const f16x8 A0 = pack8f(r0);
      const f16x8 A1 = pack8f(r1);
      f32x4 c; c[0] = 0.f; c[1] = 0.f; c[2] = 0.f; c[3] = 0.f;
      c = __builtin_amdgcn_mfma_f32_16x16x32_f16(A0, B0, c, 0, 0, 0);
      c = __builtin_amdgcn_mfma_f32_16x16x32_f16(A1, B1, c, 0, 0, 0);
      if (ln < IFEAT) {
        #pragma unroll
        for (int r = 0; r < 4; ++r) {
          const float v = tanh_u(fmaf(-2.0f, c[r], Wf));
          sv[(tile * 16 + 4 * qd + r) * 8 + ln] = (_Float16)v;
        }
      }
    }
  }
  __syncthreads();

  // ---- phase 4b: per-row gather. thread = (i, d, qtr); 8 partners each ----
  {
    const int i = t >> 3, d = (t >> 2) & 1, qtr = t & 3;
    const int mend = (qtr == 3) ? 31 : (qtr * 8 + 8);
    float sum = 0.0f;
    for (int m = qtr * 8; m < mend; ++m) {
      const int j = m + (m >= i);
      int q, row; float sgn;
      if (j > i) { q = pair_cum(i) + (j - i - 1); row = i * 31 + j - 1; sgn =  1.0f; }
      else       { q = pair_cum(j) + (i - j - 1); row = i * 31 + j;     sgn = -1.0f; }
      const h2* vp = (const h2*)(sv + q * 8 + d * 4);
      const h2 va = vp[0], vb = vp[1];
      const float4 cf = *(const float4*)(I3 + row * 8 + d * 4);
      float dot;
      dot = cf.x * (float)va.x;
      dot = fmaf(cf.y, (float)va.y, dot);
      dot = fmaf(cf.z, (float)vb.x, dot);
      dot = fmaf(cf.w, (float)vb.y, dot);
      sum = fmaf(sgn, dot, sum);
    }
    part[t] = sum;
  }
  __syncthreads();

  // ---- final: combine partials + self term + store ----
  if (t < 64) {
    const int i = t >> 1, d = t & 1;
    float sum = part[t * 4] + part[t * 4 + 1] + part[t * 4 + 2] + part[t * 4 + 3];

    float res = S2b[t] + sum;
    #pragma unroll
    for (int k = 0; k < 2; ++k) {
      const int f = d * 2 + k;
      float hs = S1b[f];
      hs = fmaf(sx[i * 4 + 0], S1W[f * 4 + 0], hs);
      hs = fmaf(sx[i * 4 + 1], S1W[f * 4 + 1], hs);
      hs = fmaf(sx[i * 4 + 2], S1W[f * 4 + 2], hs);
      hs = fmaf(sx[i * 4 + 3], S1W[f * 4 + 3], hs);
      hs = fmaxf(hs, 0.0f);
      res = fmaf(hs, S2W[i * 4 + d * 2 + k], res);
    }
    out[s * (NOBJ * 2) + t] = res;
  }
}

extern "C" void kernel_launch(void* const* d_in, const int* in_sizes, int n_in,
                              void* d_out, int out_size, void* d_ws, size_t ws_size,
                              hipStream_t stream) {
  const float* x   = (const float*)d_in[0];
  const float* L1W = (const float*)d_in[1];
  const float* L1b = (const float*)d_in[2];
  const float* L2W = (const float*)d_in[3];
  const float* L2b = (const float*)d_in[4];
  const float* I1W = (const float*)d_in[5];
  const float* I2W = (const float*)d_in[6];
  const float* I3  = (const float*)d_in[7];
  const float* S1W = (const float*)d_in[8];
  const float* S1b = (const float*)d_in[9];
  const float* S2W = (const float*)d_in[10];
  const float* S2b = (const float*)d_in[11];
  float* outp = (float*)d_out;

  magnet_fused<<<SEQ, 256, 0, stream>>>(x, L1W, L1b, L2W, L2b, I1W, I2W, I3,
                                        S1W, S1b, S2W, S2b, outp);
}

// Round 10
// 121.519 us; speedup vs baseline: 1.7227x; 1.0211x over previous
//
#include <hip/hip_runtime.h>
#include <math.h>

#define SEQ   4096
#define NOBJ  32
#define IN_F  4
#define HID   64
#define IFEAT 8
#define NPAIR_HALF 496   // 32*31/2 unordered pairs; = 31 tiles * 16
#define NTILE 31

#define TWO_LOG2E 2.8853900817779268f   // 2*log2(e)

#if __has_builtin(__builtin_amdgcn_exp2f)
  #define EXP2F(x) __builtin_amdgcn_exp2f(x)
#else
  #define EXP2F(x) exp2f(x)
#endif

typedef _Float16 h2    __attribute__((ext_vector_type(2)));
typedef _Float16 f16x8 __attribute__((ext_vector_type(8)));
typedef float    f32x4 __attribute__((ext_vector_type(4)));

__device__ __forceinline__ h2 pack2(float a, float b) {
  return __builtin_bit_cast(h2, __builtin_amdgcn_cvt_pkrtz(a, b));
}
__device__ __forceinline__ unsigned pbits(h2 v) { return __builtin_bit_cast(unsigned, v); }

__device__ __forceinline__ f16x8 pack8(float4 a, float4 b) {
  int4 v;
  v.x = (int)pbits(pack2(a.x, a.y));
  v.y = (int)pbits(pack2(a.z, a.w));
  v.z = (int)pbits(pack2(b.x, b.y));
  v.w = (int)pbits(pack2(b.z, b.w));
  return __builtin_bit_cast(f16x8, v);
}

__device__ __forceinline__ f16x8 pack8f(const float* r) {
  int4 v;
  v.x = (int)pbits(pack2(r[0], r[1]));
  v.y = (int)pbits(pack2(r[2], r[3]));
  v.z = (int)pbits(pack2(r[4], r[5]));
  v.w = (int)pbits(pack2(r[6], r[7]));
  return __builtin_bit_cast(f16x8, v);
}

// tanh via exp2: tanh(x) = 1 - 2/(exp2(x*2log2e)+1)
__device__ __forceinline__ float tanh_u(float x) {
  float e = EXP2F(x * TWO_LOG2E);
  float r = __builtin_amdgcn_rcpf(e + 1.0f);
  return fmaf(-2.0f, r, 1.0f);
}

// cumulative pair count before row i (i<j ordering): C(i) = i*(63-i)/2
__device__ __forceinline__ int pair_cum(int i) { return (i * (63 - i)) >> 1; }

__device__ __forceinline__ void pair_decode(int q, int& i, int& j) {
  int ii = (int)((63.0f - sqrtf(3969.0f - 8.0f * (float)q)) * 0.5f);
  if (ii > 0 && pair_cum(ii) > q) --ii;   // fp rounding fixups
  if (pair_cum(ii + 1) <= q)     ++ii;
  i = ii;
  j = ii + 1 + (q - pair_cum(ii));
}

// (256,4): VGPR cap 128. (256,8) caused 30MB scratch spill (R1).
__global__ __launch_bounds__(256, 4) void magnet_fused(
    const float* __restrict__ x,      // [S,32,4]
    const float* __restrict__ L1W,    // [64,4]
    const float* __restrict__ L1b,    // [64]
    const float* __restrict__ L2W,    // [64,64]
    const float* __restrict__ L2b,    // [64]
    const float* __restrict__ I1W,    // [64,64]
    const float* __restrict__ I2W,    // [8,64]
    const float* __restrict__ I3,     // [992,2,4]
    const float* __restrict__ S1W,    // [4,4]
    const float* __restrict__ S1b,    // [4]
    const float* __restrict__ S2W,    // [32,2,2]
    const float* __restrict__ S2b,    // [32,2]
    float* __restrict__ out)          // [S,32,2]
{
  // LDS layout (float units), 6400 floats = 25600 B -> 6 blocks/CU:
  //   [0,1152)     region A: sAtp [32][36] (ph1-2) / sBtp [32][36] (ph2-3,
  //                reg-buffered write) / sv [496][8] f16 (ph4a-4b)
  //   [1152,3328)  sE  [32][68] fp32 exp2(+g')
  //   [3328,5504)  sEm [32][68] fp32 exp2(-g')
  //   [5504,6016)  wB [16][32] uint I2W B-frags (ph4a) / part[256] (ph4b)
  //   [6016,6144)  sx [32][4]
  //   [6144,6152)  sW [8]
  //   [6152,6400)  ptab [496] u16 packed (i<<8|j)
  __shared__ __align__(16) float smem[6400];
  unsigned*       sAtp = (unsigned*)smem;           // [32][36]
  unsigned*       sBtp = (unsigned*)smem;           // aliases sAtp (barriered)
  _Float16*       sv   = (_Float16*)smem;           // [496][8]
  float*          sE   = smem + 1152;               // [32][68]
  float*          sEm  = smem + 3328;               // [32][68]
  unsigned*       wB   = (unsigned*)(smem + 5504);  // [16][32]
  float*          part = smem + 5504;               // [256] (aliases wB)
  float*          sx   = smem + 6016;               // [32][4]
  float*          sW   = smem + 6144;               // [8]
  unsigned short* ptab = (unsigned short*)(smem + 6152); // [496]

  const int t = threadIdx.x;
  const int s = blockIdx.x;

  if (t < NOBJ * IN_F) sx[t] = x[s * (NOBJ * IN_F) + t];
  if (t < IFEAT) {                   // W[f] = sum_h I2W[f][h] (fp32)
    float a = 0.0f;
    const float4* w = (const float4*)(I2W + t * HID);
    #pragma unroll
    for (int c = 0; c < 16; ++c) { float4 v = w[c]; a += (v.x + v.y) + (v.z + v.w); }
    sW[t] = a;
  }
  #pragma unroll
  for (int idx = t; idx < 512; idx += 256) {   // wB[n][k2]; rows 8-15 zero
    const int n = idx >> 5, k2 = idx & 31;
    wB[idx] = (n < IFEAT)
      ? pbits(pack2(I2W[n * HID + 2 * k2], I2W[n * HID + 2 * k2 + 1])) : 0u;
  }
  #pragma unroll
  for (int q = t; q < NPAIR_HALF; q += 256) {  // pair table (kills 4a decode)
    int i, j; pair_decode(q, i, j);
    ptab[q] = (unsigned short)((i << 8) | j);
  }
  __syncthreads();

  // ---- phase 1: h1 = relu(x @ L1W^T + L1b) fp32, pack f16 -> sAtp[n][k2] ----
  {
    const int n = t & 31, gI = t >> 5, kb = gI * 8;
    const float x0 = sx[n * 4 + 0], x1 = sx[n * 4 + 1];
    const float x2 = sx[n * 4 + 2], x3 = sx[n * 4 + 3];
    float a[8];
    #pragma unroll
    for (int r = 0; r < 8; ++r) {
      const int k = kb + r;
      const float4 w = *(const float4*)(L1W + k * 4);
      float v = L1b[k];
      v = fmaf(x0, w.x, v); v = fmaf(x1, w.y, v);
      v = fmaf(x2, w.z, v); v = fmaf(x3, w.w, v);
      a[r] = fmaxf(v, 0.0f);
    }
    int4 pk;
    pk.x = (int)pbits(pack2(a[0], a[1]));
    pk.y = (int)pbits(pack2(a[2], a[3]));
    pk.z = (int)pbits(pack2(a[4], a[5]));
    pk.w = (int)pbits(pack2(a[6], a[7]));
    *(int4*)(sAtp + n * 36 + gI * 4) = pk;
  }
  __syncthreads();

  const int lane = t & 63;
  const int wv   = t >> 6;        // wave id
  const int qd   = lane >> 4;     // quad 0..3
  const int ln   = lane & 15;

  // ---- phase 2: h2 = relu(h1 @ L2W^T + L2b) via MFMA; reg-buffer, then
  // write packed h2 over the (dead) sAtp region as sBtp[n][k2]. ----
  {
    const int m = 16 * wv + ln;
    const float* wr = L2W + m * HID;
    const f16x8 A0 = pack8(*(const float4*)(wr + 8 * qd),
                           *(const float4*)(wr + 8 * qd + 4));
    const f16x8 A1 = pack8(*(const float4*)(wr + 32 + 8 * qd),
                           *(const float4*)(wr + 32 + 8 * qd + 4));
    const float4 bias = *(const float4*)(L2b + 16 * wv + 4 * qd);
    unsigned pk[4];
    #pragma unroll
    for (int nt = 0; nt < 2; ++nt) {
      const int n = nt * 16 + ln;
      const f16x8 B0 = __builtin_bit_cast(f16x8, *(const int4*)(sAtp + n * 36 + 4 * qd));
      const f16x8 B1 = __builtin_bit_cast(f16x8, *(const int4*)(sAtp + n * 36 + 16 + 4 * qd));
      f32x4 c; c[0] = bias.x; c[1] = bias.y; c[2] = bias.z; c[3] = bias.w;
      c = __builtin_amdgcn_mfma_f32_16x16x32_f16(A0, B0, c, 0, 0, 0);
      c = __builtin_amdgcn_mfma_f32_16x16x32_f16(A1, B1, c, 0, 0, 0);
      pk[nt * 2]     = pbits(pack2(fmaxf(c[0], 0.f), fmaxf(c[1], 0.f)));
      pk[nt * 2 + 1] = pbits(pack2(fmaxf(c[2], 0.f), fmaxf(c[3], 0.f)));
    }
    __syncthreads();   // all sAtp reads done before overwrite
    #pragma unroll
    for (int nt = 0; nt < 2; ++nt) {
      const int n = nt * 16 + ln;
      sBtp[n * 36 + 8 * wv + 2 * qd]     = pk[nt * 2];
      sBtp[n * 36 + 8 * wv + 2 * qd + 1] = pk[nt * 2 + 1];
    }
  }
  __syncthreads();

  // ---- phase 3: g = h2 @ I1W^T via MFMA; store E=exp2(g'), Em=exp2(-g') ----
  {
    const int m = 16 * wv + ln;
    const float* wr = I1W + m * HID;
    const f16x8 A0 = pack8(*(const float4*)(wr + 8 * qd),
                           *(const float4*)(wr + 8 * qd + 4));
    const f16x8 A1 = pack8(*(const float4*)(wr + 32 + 8 * qd),
                           *(const float4*)(wr + 32 + 8 * qd + 4));
    #pragma unroll
    for (int nt = 0; nt < 2; ++nt) {
      const int n = nt * 16 + ln;
      const f16x8 B0 = __builtin_bit_cast(f16x8, *(const int4*)(sBtp + n * 36 + 4 * qd));
      const f16x8 B1 = __builtin_bit_cast(f16x8, *(const int4*)(sBtp + n * 36 + 16 + 4 * qd));
      f32x4 c; c[0] = 0.f; c[1] = 0.f; c[2] = 0.f; c[3] = 0.f;
      c = __builtin_amdgcn_mfma_f32_16x16x32_f16(A0, B0, c, 0, 0, 0);
      c = __builtin_amdgcn_mfma_f32_16x16x32_f16(A1, B1, c, 0, 0, 0);
      #pragma unroll
      for (int r = 0; r < 4; ++r) {
        const int mo = 16 * wv + 4 * qd + r;
        float gp = fminf(fmaxf(c[r] * TWO_LOG2E, -60.0f), 60.0f);
        sE [n * 68 + mo] = EXP2F(gp);
        sEm[n * 68 + mo] = EXP2F(-gp);
      }
    }
  }
  __syncthreads();   // also protects sBtp (region A) before sv writes in 4a

  // ---- phase 4a: pair dots via MFMA. A[m=pair][k=h] = r (f16), B = I2W.
  // r = rcp(Ei*Emj+1); u = W - 2c; v = tanh(u) -> sv[p][f], lanes ln<8. ----
  {
    const f16x8 B0 = __builtin_bit_cast(f16x8, *(const int4*)(wB + ln * 32 + 4 * qd));
    const f16x8 B1 = __builtin_bit_cast(f16x8, *(const int4*)(wB + ln * 32 + 16 + 4 * qd));
    const float Wf = sW[ln & 7];

    for (int tile = wv; tile < NTILE; tile += 4) {
      const unsigned pij = ptab[tile * 16 + ln];   // broadcast across qd
      const int i = pij >> 8, j = pij & 255;
      const float* Ei = sE  + i * 68 + qd * 8;
      const float* Mj = sEm + j * 68 + qd * 8;
      const float4 e0 = *(const float4*)(Ei);
      const float4 e1 = *(const float4*)(Ei + 4);
      const float4 e2 = *(const float4*)(Ei + 32);
      const float4 e3 = *(const float4*)(Ei + 36);
      const float4 m0 = *(const float4*)(Mj);
      const float4 m1 = *(const float4*)(Mj + 4);
      const float4 m2 = *(const float4*)(Mj + 32);
      const float4 m3 = *(const float4*)(Mj + 36);
      float r0[8], r1[8];
      #pragma unroll
      for (int c = 0; c < 4; ++c) {
        r0[c]     = __builtin_amdgcn_rcpf(fmaf((&e0.x)[c], (&m0.x)[c], 1.0f));
        r0[4 + c] = __builtin_amdgcn_rcpf(fmaf((&e1.x)[c], (&m1.x)[c], 1.0f));
        r1[c]     = __builtin_amdgcn_rcpf(fmaf((&e2.x)[c], (&m2.x)[c], 1.0f));
        r1[4 + c] = __builtin_amdgcn_rcpf(fmaf((&e3.x)[c], (&m3.x)[c], 1.0f));
      }
      const f16x8 A0 = pack8f(r0);
      const f16x8 A1 = pack8f(r1);
      f32x4 c; c[0] = 0.f; c[1] = 0.f; c[2] = 0.f; c[3] = 0.f;
      c = __builtin_amdgcn_mfma_f32_16x16x32_f16(A0, B0, c, 0, 0, 0);
      c = __builtin_amdgcn_mfma_f32_16x16x32_f16(A1, B1, c, 0, 0, 0);
      if (ln < IFEAT) {
        #pragma unroll
        for (int r = 0; r < 4; ++r) {
          const float v = tanh_u(fmaf(-2.0f, c[r], Wf));
          sv[(tile * 16 + 4 * qd + r) * 8 + ln] = (_Float16)v;
        }
      }
    }
  }
  __syncthreads();   // sv complete; wB dead -> part may overwrite

  // ---- phase 4b: per-row gather. thread = (i, d, qtr); 8 partners each ----
  {
    const int i = t >> 3, d = (t >> 2) & 1, qtr = t & 3;
    const int mend = (qtr == 3) ? 31 : (qtr * 8 + 8);
    float sum = 0.0f;
    for (int m = qtr * 8; m < mend; ++m) {
      const int j = m + (m >= i);
      int q; float sgn;
      if (j > i) { q = pair_cum(i) + (j - i - 1); sgn =  1.0f; }
      else       { q = pair_cum(j) + (i - j - 1); sgn = -1.0f; }
      const h2* vp = (const h2*)(sv + q * 8 + d * 4);
      const h2 va = vp[0], vb = vp[1];
      const float4 cf = *(const float4*)(I3 + (i * 31 + m) * 8 + d * 4);
      float dot;
      dot = cf.x * (float)va.x;
      dot = fmaf(cf.y, (float)va.y, dot);
      dot = fmaf(cf.z, (float)vb.x, dot);
      dot = fmaf(cf.w, (float)vb.y, dot);
      sum = fmaf(sgn, dot, sum);
    }
    part[t] = sum;
  }
  __syncthreads();

  // ---- final: combine partials + self term + store ----
  if (t < 64) {
    const int i = t >> 1, d = t & 1;
    float sum = part[t * 4] + part[t * 4 + 1] + part[t * 4 + 2] + part[t * 4 + 3];

    float res = S2b[t] + sum;
    #pragma unroll
    for (int k = 0; k < 2; ++k) {
      const int f = d * 2 + k;
      float hs = S1b[f];
      hs = fmaf(sx[i * 4 + 0], S1W[f * 4 + 0], hs);
      hs = fmaf(sx[i * 4 + 1], S1W[f * 4 + 1], hs);
      hs = fmaf(sx[i * 4 + 2], S1W[f * 4 + 2], hs);
      hs = fmaf(sx[i * 4 + 3], S1W[f * 4 + 3], hs);
      hs = fmaxf(hs, 0.0f);
      res = fmaf(hs, S2W[i * 4 + d * 2 + k], res);
    }
    out[s * (NOBJ * 2) + t] = res;
  }
}

extern "C" void kernel_launch(void* const* d_in, const int* in_sizes, int n_in,
                              void* d_out, int out_size, void* d_ws, size_t ws_size,
                              hipStream_t stream) {
  const float* x   = (const float*)d_in[0];
  const float* L1W = (const float*)d_in[1];
  const float* L1b = (const float*)d_in[2];
  const float* L2W = (const float*)d_in[3];
  const float* L2b = (const float*)d_in[4];
  const float* I1W = (const float*)d_in[5];
  const float* I2W = (const float*)d_in[6];
  const float* I3  = (const float*)d_in[7];
  const float* S1W = (const float*)d_in[8];
  const float* S1b = (const float*)d_in[9];
  const float* S2W = (const float*)d_in[10];
  const float* S2b = (const float*)d_in[11];
  float* outp = (float*)d_out;

  magnet_fused<<<SEQ, 256, 0, stream>>>(x, L1W, L1b, L2W, L2b, I1W, I2W, I3,
                                        S1W, S1b, S2W, S2b, outp);
}

// Round 11
// 119.154 us; speedup vs baseline: 1.7569x; 1.0198x over previous
//
#include <hip/hip_runtime.h>
#include <math.h>

#define SEQ   4096
#define NOBJ  32
#define IN_F  4
#define HID   64
#define IFEAT 8
#define NPAIR_HALF 496   // 32*31/2 unordered pairs; = 31 tiles * 16
#define NTILE 31

#define TWO_LOG2E 2.8853900817779268f   // 2*log2(e)

#if __has_builtin(__builtin_amdgcn_exp2f)
  #define EXP2F(x) __builtin_amdgcn_exp2f(x)
#else
  #define EXP2F(x) exp2f(x)
#endif

typedef _Float16 h2    __attribute__((ext_vector_type(2)));
typedef _Float16 f16x8 __attribute__((ext_vector_type(8)));
typedef float    f32x4 __attribute__((ext_vector_type(4)));

__device__ __forceinline__ h2 pack2(float a, float b) {
  return __builtin_bit_cast(h2, __builtin_amdgcn_cvt_pkrtz(a, b));
}
__device__ __forceinline__ unsigned pbits(h2 v) { return __builtin_bit_cast(unsigned, v); }

__device__ __forceinline__ f16x8 pack8(float4 a, float4 b) {
  int4 v;
  v.x = (int)pbits(pack2(a.x, a.y));
  v.y = (int)pbits(pack2(a.z, a.w));
  v.z = (int)pbits(pack2(b.x, b.y));
  v.w = (int)pbits(pack2(b.z, b.w));
  return __builtin_bit_cast(f16x8, v);
}

__device__ __forceinline__ f16x8 pack8f(const float* r) {
  int4 v;
  v.x = (int)pbits(pack2(r[0], r[1]));
  v.y = (int)pbits(pack2(r[2], r[3]));
  v.z = (int)pbits(pack2(r[4], r[5]));
  v.w = (int)pbits(pack2(r[6], r[7]));
  return __builtin_bit_cast(f16x8, v);
}

// tanh via exp2: tanh(x) = 1 - 2/(exp2(x*2log2e)+1)
__device__ __forceinline__ float tanh_u(float x) {
  float e = EXP2F(x * TWO_LOG2E);
  float r = __builtin_amdgcn_rcpf(e + 1.0f);
  return fmaf(-2.0f, r, 1.0f);
}

// cumulative pair count before row i (i<j ordering): C(i) = i*(63-i)/2
__device__ __forceinline__ int pair_cum(int i) { return (i * (63 - i)) >> 1; }

__device__ __forceinline__ void pair_decode(int q, int& i, int& j) {
  int ii = (int)((63.0f - sqrtf(3969.0f - 8.0f * (float)q)) * 0.5f);
  if (ii > 0 && pair_cum(ii) > q) --ii;   // fp rounding fixups
  if (pair_cum(ii + 1) <= q)     ++ii;
  i = ii;
  j = ii + 1 + (q - pair_cum(ii));
}

// (256,4): VGPR cap 128. (256,8) caused 30MB scratch spill (R1).
// LDS 16896 B -> 8 blocks/CU (wave-slot limited); VGPR=40 not limiting.
__global__ __launch_bounds__(256, 4) void magnet_fused(
    const float* __restrict__ x,      // [S,32,4]
    const float* __restrict__ L1W,    // [64,4]
    const float* __restrict__ L1b,    // [64]
    const float* __restrict__ L2W,    // [64,64]
    const float* __restrict__ L2b,    // [64]
    const float* __restrict__ I1W,    // [64,64]
    const float* __restrict__ I2W,    // [8,64]
    const float* __restrict__ I3,     // [992,2,4]
    const float* __restrict__ S1W,    // [4,4]
    const float* __restrict__ S1b,    // [4]
    const float* __restrict__ S2W,    // [32,2,2]
    const float* __restrict__ S2b,    // [32,2]
    float* __restrict__ out)          // [S,32,2]
{
  // LDS layout (float units), 4224 floats = 16896 B:
  //   [0,1152)     region A: sAtp [32][36] (ph1-2) / sBtp (ph2-3, barriered
  //                alias) / sv [496][8] f16 (ph4a-4b; 992 floats)
  //   [1152,3328)  sE  [32][68] fp32 exp2(+g')   (Em = 1/E, never stored:
  //                r = 1/(Ei*Emj+1) == Ej*rcp(Ei+Ej))
  //   [3328,3840)  wB [16][32] uint I2W B-frags (ph4a) / part[256] (ph4b)
  //   [3840,3968)  sx [32][4]
  //   [3968,3976)  sW [8]
  //   [3976,4224)  ptab [496] u16 packed (i<<8|j)
  __shared__ __align__(16) float smem[4224];
  unsigned*       sAtp = (unsigned*)smem;           // [32][36]
  unsigned*       sBtp = (unsigned*)smem;           // aliases sAtp (barriered)
  _Float16*       sv   = (_Float16*)smem;           // [496][8]
  float*          sE   = smem + 1152;               // [32][68]
  unsigned*       wB   = (unsigned*)(smem + 3328);  // [16][32]
  float*          part = smem + 3328;               // [256] (aliases wB)
  float*          sx   = smem + 3840;               // [32][4]
  float*          sW   = smem + 3968;               // [8]
  unsigned short* ptab = (unsigned short*)(smem + 3976); // [496]

  const int t = threadIdx.x;
  const int s = blockIdx.x;

  if (t < NOBJ * IN_F) sx[t] = x[s * (NOBJ * IN_F) + t];
  if (t < IFEAT) {                   // W[f] = sum_h I2W[f][h] (fp32)
    float a = 0.0f;
    const float4* w = (const float4*)(I2W + t * HID);
    #pragma unroll
    for (int c = 0; c < 16; ++c) { float4 v = w[c]; a += (v.x + v.y) + (v.z + v.w); }
    sW[t] = a;
  }
  #pragma unroll
  for (int idx = t; idx < 512; idx += 256) {   // wB[n][k2]; rows 8-15 zero
    const int n = idx >> 5, k2 = idx & 31;
    wB[idx] = (n < IFEAT)
      ? pbits(pack2(I2W[n * HID + 2 * k2], I2W[n * HID + 2 * k2 + 1])) : 0u;
  }
  #pragma unroll
  for (int q = t; q < NPAIR_HALF; q += 256) {  // pair table (kills 4a decode)
    int i, j; pair_decode(q, i, j);
    ptab[q] = (unsigned short)((i << 8) | j);
  }
  __syncthreads();

  // ---- phase 1: h1 = relu(x @ L1W^T + L1b) fp32, pack f16 -> sAtp[n][k2] ----
  {
    const int n = t & 31, gI = t >> 5, kb = gI * 8;
    const float x0 = sx[n * 4 + 0], x1 = sx[n * 4 + 1];
    const float x2 = sx[n * 4 + 2], x3 = sx[n * 4 + 3];
    float a[8];
    #pragma unroll
    for (int r = 0; r < 8; ++r) {
      const int k = kb + r;
      const float4 w = *(const float4*)(L1W + k * 4);
      float v = L1b[k];
      v = fmaf(x0, w.x, v); v = fmaf(x1, w.y, v);
      v = fmaf(x2, w.z, v); v = fmaf(x3, w.w, v);
      a[r] = fmaxf(v, 0.0f);
    }
    int4 pk;
    pk.x = (int)pbits(pack2(a[0], a[1]));
    pk.y = (int)pbits(pack2(a[2], a[3]));
    pk.z = (int)pbits(pack2(a[4], a[5]));
    pk.w = (int)pbits(pack2(a[6], a[7]));
    *(int4*)(sAtp + n * 36 + gI * 4) = pk;
  }
  __syncthreads();

  const int lane = t & 63;
  const int wv   = t >> 6;        // wave id
  const int qd   = lane >> 4;     // quad 0..3
  const int ln   = lane & 15;

  // ---- phase 2: h2 = relu(h1 @ L2W^T + L2b) via MFMA; reg-buffer, then
  // write packed h2 over the (dead) sAtp region as sBtp[n][k2]. ----
  {
    const int m = 16 * wv + ln;
    const float* wr = L2W + m * HID;
    const f16x8 A0 = pack8(*(const float4*)(wr + 8 * qd),
                           *(const float4*)(wr + 8 * qd + 4));
    const f16x8 A1 = pack8(*(const float4*)(wr + 32 + 8 * qd),
                           *(const float4*)(wr + 32 + 8 * qd + 4));
    const float4 bias = *(const float4*)(L2b + 16 * wv + 4 * qd);
    unsigned pk[4];
    #pragma unroll
    for (int nt = 0; nt < 2; ++nt) {
      const int n = nt * 16 + ln;
      const f16x8 B0 = __builtin_bit_cast(f16x8, *(const int4*)(sAtp + n * 36 + 4 * qd));
      const f16x8 B1 = __builtin_bit_cast(f16x8, *(const int4*)(sAtp + n * 36 + 16 + 4 * qd));
      f32x4 c; c[0] = bias.x; c[1] = bias.y; c[2] = bias.z; c[3] = bias.w;
      c = __builtin_amdgcn_mfma_f32_16x16x32_f16(A0, B0, c, 0, 0, 0);
      c = __builtin_amdgcn_mfma_f32_16x16x32_f16(A1, B1, c, 0, 0, 0);
      pk[nt * 2]     = pbits(pack2(fmaxf(c[0], 0.f), fmaxf(c[1], 0.f)));
      pk[nt * 2 + 1] = pbits(pack2(fmaxf(c[2], 0.f), fmaxf(c[3], 0.f)));
    }
    __syncthreads();   // all sAtp reads done before overwrite
    #pragma unroll
    for (int nt = 0; nt < 2; ++nt) {
      const int n = nt * 16 + ln;
      sBtp[n * 36 + 8 * wv + 2 * qd]     = pk[nt * 2];
      sBtp[n * 36 + 8 * wv + 2 * qd + 1] = pk[nt * 2 + 1];
    }
  }
  __syncthreads();

  // ---- phase 3: g = h2 @ I1W^T via MFMA; store E = exp2(g') only ----
  {
    const int m = 16 * wv + ln;
    const float* wr = I1W + m * HID;
    const f16x8 A0 = pack8(*(const float4*)(wr + 8 * qd),
                           *(const float4*)(wr + 8 * qd + 4));
    const f16x8 A1 = pack8(*(const float4*)(wr + 32 + 8 * qd),
                           *(const float4*)(wr + 32 + 8 * qd + 4));
    #pragma unroll
    for (int nt = 0; nt < 2; ++nt) {
      const int n = nt * 16 + ln;
      const f16x8 B0 = __builtin_bit_cast(f16x8, *(const int4*)(sBtp + n * 36 + 4 * qd));
      const f16x8 B1 = __builtin_bit_cast(f16x8, *(const int4*)(sBtp + n * 36 + 16 + 4 * qd));
      f32x4 c; c[0] = 0.f; c[1] = 0.f; c[2] = 0.f; c[3] = 0.f;
      c = __builtin_amdgcn_mfma_f32_16x16x32_f16(A0, B0, c, 0, 0, 0);
      c = __builtin_amdgcn_mfma_f32_16x16x32_f16(A1, B1, c, 0, 0, 0);
      #pragma unroll
      for (int r = 0; r < 4; ++r) {
        const int mo = 16 * wv + 4 * qd + r;
        float gp = fminf(fmaxf(c[r] * TWO_LOG2E, -60.0f), 60.0f);
        sE[n * 68 + mo] = EXP2F(gp);
      }
    }
  }
  __syncthreads();   // also protects sBtp (region A) before sv writes in 4a

  // ---- phase 4a: pair dots via MFMA. A[m=pair][k=h] = r (f16), B = I2W.
  // r = Ej*rcp(Ei+Ej)  (== 1/(Ei/Ej+1)); u = W - 2c; v = tanh(u) -> sv ----
  {
    const f16x8 B0 = __builtin_bit_cast(f16x8, *(const int4*)(wB + ln * 32 + 4 * qd));
    const f16x8 B1 = __builtin_bit_cast(f16x8, *(const int4*)(wB + ln * 32 + 16 + 4 * qd));
    const float Wf = sW[ln & 7];

    for (int tile = wv; tile < NTILE; tile += 4) {
      const unsigned pij = ptab[tile * 16 + ln];   // broadcast across qd
      const int i = pij >> 8, j = pij & 255;
      const float* Ei = sE + i * 68 + qd * 8;
      const float* Ej = sE + j * 68 + qd * 8;
      const float4 e0 = *(const float4*)(Ei);
      const float4 e1 = *(const float4*)(Ei + 4);
      const float4 e2 = *(const float4*)(Ei + 32);
      const float4 e3 = *(const float4*)(Ei + 36);
      const float4 f0 = *(const float4*)(Ej);
      const float4 f1 = *(const float4*)(Ej + 4);
      const float4 f2 = *(const float4*)(Ej + 32);
      const float4 f3 = *(const float4*)(Ej + 36);
      float r0[8], r1[8];
      #pragma unroll
      for (int c = 0; c < 4; ++c) {
        r0[c]     = (&f0.x)[c] * __builtin_amdgcn_rcpf((&e0.x)[c] + (&f0.x)[c]);
        r0[4 + c] = (&f1.x)[c] * __builtin_amdgcn_rcpf((&e1.x)[c] + (&f1.x)[c]);
        r1[c]     = (&f2.x)[c] * __builtin_amdgcn_rcpf((&e2.x)[c] + (&f2.x)[c]);
        r1[4 + c] = (&f3.x)[c] * __builtin_amdgcn_rcpf((&e3.x)[c] + (&f3.x)[c]);
      }
      const f16x8 A0 = pack8f(r0);
      const f16x8 A1 = pack8f(r1);
      f32x4 c; c[0] = 0.f; c[1] = 0.f; c[2] = 0.f; c[3] = 0.f;
      c = __builtin_amdgcn_mfma_f32_16x16x32_f16(A0, B0, c, 0, 0, 0);
      c = __builtin_amdgcn_mfma_f32_16x16x32_f16(A1, B1, c, 0, 0, 0);
      if (ln < IFEAT) {
        #pragma unroll
        for (int r = 0; r < 4; ++r) {
          const float v = tanh_u(fmaf(-2.0f, c[r], Wf));
          sv[(tile * 16 + 4 * qd + r) * 8 + ln] = (_Float16)v;
        }
      }
    }
  }
  __syncthreads();   // sv complete; wB dead -> part may overwrite

  // ---- phase 4b: per-row gather. thread = (i, d, qtr); 8 partners each ----
  {
    const int i = t >> 3, d = (t >> 2) & 1, qtr = t & 3;
    const int mend = (qtr == 3) ? 31 : (qtr * 8 + 8);
    float sum = 0.0f;
    for (int m = qtr * 8; m < mend; ++m) {
      const int j = m + (m >= i);
      int q; float sgn;
      if (j > i) { q = pair_cum(i) + (j - i - 1); sgn =  1.0f; }
      else       { q = pair_cum(j) + (i - j - 1); sgn = -1.0f; }
      const h2* vp = (const h2*)(sv + q * 8 + d * 4);
      const h2 va = vp[0], vb = vp[1];
      const float4 cf = *(const float4*)(I3 + (i * 31 + m) * 8 + d * 4);
      float dot;
      dot = cf.x * (float)va.x;
      dot = fmaf(cf.y, (float)va.y, dot);
      dot = fmaf(cf.z, (float)vb.x, dot);
      dot = fmaf(cf.w, (float)vb.y, dot);
      sum = fmaf(sgn, dot, sum);
    }
    part[t] = sum;
  }
  __syncthreads();

  // ---- final: combine partials + self term + store ----
  if (t < 64) {
    const int i = t >> 1, d = t & 1;
    float sum = part[t * 4] + part[t * 4 + 1] + part[t * 4 + 2] + part[t * 4 + 3];

    float res = S2b[t] + sum;
    #pragma unroll
    for (int k = 0; k < 2; ++k) {
      const int f = d * 2 + k;
      float hs = S1b[f];
      hs = fmaf(sx[i * 4 + 0], S1W[f * 4 + 0], hs);
      hs = fmaf(sx[i * 4 + 1], S1W[f * 4 + 1], hs);
      hs = fmaf(sx[i * 4 + 2], S1W[f * 4 + 2], hs);
      hs = fmaf(sx[i * 4 + 3], S1W[f * 4 + 3], hs);
      hs = fmaxf(hs, 0.0f);
      res = fmaf(hs, S2W[i * 4 + d * 2 + k], res);
    }
    out[s * (NOBJ * 2) + t] = res;
  }
}

extern "C" void kernel_launch(void* const* d_in, const int* in_sizes, int n_in,
                              void* d_out, int out_size, void* d_ws, size_t ws_size,
                              hipStream_t stream) {
  const float* x   = (const float*)d_in[0];
  const float* L1W = (const float*)d_in[1];
  const float* L1b = (const float*)d_in[2];
  const float* L2W = (const float*)d_in[3];
  const float* L2b = (const float*)d_in[4];
  const float* I1W = (const float*)d_in[5];
  const float* I2W = (const float*)d_in[6];
  const float* I3  = (const float*)d_in[7];
  const float* S1W = (const float*)d_in[8];
  const float* S1b = (const float*)d_in[9];
  const float* S2W = (const float*)d_in[10];
  const float* S2b = (const float*)d_in[11];
  float* outp = (float*)d_out;

  magnet_fused<<<SEQ, 256, 0, stream>>>(x, L1W, L1b, L2W, L2b, I1W, I2W, I3,
                                        S1W, S1b, S2W, S2b, outp);
}

// Round 13
// 117.890 us; speedup vs baseline: 1.7757x; 1.0107x over previous
//
#include <hip/hip_runtime.h>
#include <math.h>

#define SEQ   4096
#define NOBJ  32
#define IN_F  4
#define HID   64
#define IFEAT 8
#define NPAIR_HALF 496   // 32*31/2 unordered pairs; = 31 tiles * 16
#define NTILE 31

#define TWO_LOG2E 2.8853900817779268f   // 2*log2(e)

#if __has_builtin(__builtin_amdgcn_exp2f)
  #define EXP2F(x) __builtin_amdgcn_exp2f(x)
#else
  #define EXP2F(x) exp2f(x)
#endif

typedef _Float16 h2    __attribute__((ext_vector_type(2)));
typedef _Float16 f16x8 __attribute__((ext_vector_type(8)));
typedef float    f32x4 __attribute__((ext_vector_type(4)));

__device__ __forceinline__ h2 pack2(float a, float b) {
  return __builtin_bit_cast(h2, __builtin_amdgcn_cvt_pkrtz(a, b));
}
__device__ __forceinline__ unsigned pbits(h2 v) { return __builtin_bit_cast(unsigned, v); }

__device__ __forceinline__ f16x8 pack8(float4 a, float4 b) {
  int4 v;
  v.x = (int)pbits(pack2(a.x, a.y));
  v.y = (int)pbits(pack2(a.z, a.w));
  v.z = (int)pbits(pack2(b.x, b.y));
  v.w = (int)pbits(pack2(b.z, b.w));
  return __builtin_bit_cast(f16x8, v);
}

__device__ __forceinline__ f16x8 pack8f(const float* r) {
  int4 v;
  v.x = (int)pbits(pack2(r[0], r[1]));
  v.y = (int)pbits(pack2(r[2], r[3]));
  v.z = (int)pbits(pack2(r[4], r[5]));
  v.w = (int)pbits(pack2(r[6], r[7]));
  return __builtin_bit_cast(f16x8, v);
}

// tanh via exp2: tanh(x) = 1 - 2/(exp2(x*2log2e)+1)
__device__ __forceinline__ float tanh_u(float x) {
  float e = EXP2F(x * TWO_LOG2E);
  float r = __builtin_amdgcn_rcpf(e + 1.0f);
  return fmaf(-2.0f, r, 1.0f);
}

// cumulative pair count before row i (i<j ordering): C(i) = i*(63-i)/2
__device__ __forceinline__ int pair_cum(int i) { return (i * (63 - i)) >> 1; }

__device__ __forceinline__ void pair_decode(int q, int& i, int& j) {
  int ii = (int)((63.0f - sqrtf(3969.0f - 8.0f * (float)q)) * 0.5f);
  if (ii > 0 && pair_cum(ii) > q) --ii;   // fp rounding fixups
  if (pair_cum(ii + 1) <= q)     ++ii;
  i = ii;
  j = ii + 1 + (q - pair_cum(ii));
}

// 2 sequence positions per block: amortizes weight loads / A-frag packs /
// table init across s, halves barriers per s, doubles per-wave ILP.
// (256,4): VGPR cap 128 ((256,8) spilled 30MB in R1).
__global__ __launch_bounds__(256, 4) void magnet_fused(
    const float* __restrict__ x,      // [S,32,4]
    const float* __restrict__ L1W,    // [64,4]
    const float* __restrict__ L1b,    // [64]
    const float* __restrict__ L2W,    // [64,64]
    const float* __restrict__ L2b,    // [64]
    const float* __restrict__ I1W,    // [64,64]
    const float* __restrict__ I2W,    // [8,64]
    const float* __restrict__ I3,     // [992,2,4]
    const float* __restrict__ S1W,    // [4,4]
    const float* __restrict__ S1b,    // [4]
    const float* __restrict__ S2W,    // [32,2,2]
    const float* __restrict__ S2b,    // [32,2]
    float* __restrict__ out)          // [S,32,2]
{
  // LDS layout (float units), 9728 floats = 38912 B -> 4 blocks/CU.
  // R11 BUG FIX: sv is f16[496][8] = 1984 FLOATS per ss (not 1152). sv s0
  // occupies A s0 + A s1 (dead after ph3); sv s1 gets a dedicated region.
  //   [0,1152)     A s0: sAtp/sBtp s0 (barriered alias)
  //   [1152,2304)  A s1: sAtp/sBtp s1
  //   [0,1984)     sv s0 (ph4a-4b; aliases A s0+s1)
  //   [2304,4480)  sE s0 [32][68] fp32 exp2(+g')   (r = Ej*rcp(Ei+Ej))
  //   [4480,6656)  sE s1
  //   [6656,8640)  sv s1 (dedicated)
  //   [8640,9152)  wB [16][32] uint I2W B-frags / part[256] (4b alias)
  //   [9152,9408)  sx [2][32][4]
  //   [9408,9416)  sW [8]
  //   [9416,9664)  ptab [496] u16 (i<<8|j)
  //   [9664,9728)  swpart [64]
  __shared__ __align__(16) float smem[9728];
  float*          sE0  = smem + 2304;
  unsigned*       wB   = (unsigned*)(smem + 8640);  // [16][32]
  float*          part = smem + 8640;               // [256] (aliases wB)
  float*          sx   = smem + 9152;               // [2][32][4]
  float*          sW   = smem + 9408;               // [8]
  unsigned short* ptab = (unsigned short*)(smem + 9416); // [496]
  float*          swpart = smem + 9664;             // [64]

  const int t  = threadIdx.x;
  const int s0 = blockIdx.x * 2;

  // ---- init ----
  sx[t] = x[s0 * 128 + t];                     // 256 floats = 2 seq positions
  if (t < 64) {                                // sW partials (distributed)
    const int f = t >> 3, seg = t & 7;
    const float4 a = *(const float4*)(I2W + f * HID + seg * 8);
    const float4 b = *(const float4*)(I2W + f * HID + seg * 8 + 4);
    swpart[t] = ((a.x + a.y) + (a.z + a.w)) + ((b.x + b.y) + (b.z + b.w));
  }
  #pragma unroll
  for (int idx = t; idx < 512; idx += 256) {   // wB[n][k2]; rows 8-15 zero
    const int n = idx >> 5, k2 = idx & 31;
    wB[idx] = (n < IFEAT)
      ? pbits(pack2(I2W[n * HID + 2 * k2], I2W[n * HID + 2 * k2 + 1])) : 0u;
  }
  #pragma unroll
  for (int q = t; q < NPAIR_HALF; q += 256) {  // pair table (kills 4a decode)
    int i, j; pair_decode(q, i, j);
    ptab[q] = (unsigned short)((i << 8) | j);
  }
  __syncthreads();
  if (t < IFEAT) {                             // combine sW partials
    float a = 0.0f;
    #pragma unroll
    for (int c = 0; c < 8; ++c) a += swpart[t * 8 + c];
    sW[t] = a;                                 // read in 4a (barriers cover)
  }

  // ---- phase 1: h1 = relu(x @ L1W^T + L1b), pack f16 -> sAtp(ss)[n][k2] ----
  {
    const int n = t & 31, gI = t >> 5, kb = gI * 8;
    float a[2][8];
    #pragma unroll
    for (int r = 0; r < 8; ++r) {
      const int k = kb + r;
      const float4 w = *(const float4*)(L1W + k * 4);   // shared across ss
      const float bias = L1b[k];
      #pragma unroll
      for (int ss = 0; ss < 2; ++ss) {
        const float* xv = sx + ss * 128 + n * 4;
        float v = bias;
        v = fmaf(xv[0], w.x, v); v = fmaf(xv[1], w.y, v);
        v = fmaf(xv[2], w.z, v); v = fmaf(xv[3], w.w, v);
        a[ss][r] = fmaxf(v, 0.0f);
      }
    }
    #pragma unroll
    for (int ss = 0; ss < 2; ++ss) {
      unsigned* sAtp = (unsigned*)(smem + ss * 1152);
      int4 pk;
      pk.x = (int)pbits(pack2(a[ss][0], a[ss][1]));
      pk.y = (int)pbits(pack2(a[ss][2], a[ss][3]));
      pk.z = (int)pbits(pack2(a[ss][4], a[ss][5]));
      pk.w = (int)pbits(pack2(a[ss][6], a[ss][7]));
      *(int4*)(sAtp + n * 36 + gI * 4) = pk;
    }
  }
  __syncthreads();

  const int lane = t & 63;
  const int wv   = t >> 6;        // wave id
  const int qd   = lane >> 4;     // quad 0..3
  const int ln   = lane & 15;

  // ---- phase 2: h2 = relu(h1 @ L2W^T + L2b) via MFMA; reg-buffer both ss,
  // then overwrite region A as sBtp(ss)[n][k2]. A-frags shared across ss. ----
  {
    const int m = 16 * wv + ln;
    const float* wr = L2W + m * HID;
    const f16x8 A0 = pack8(*(const float4*)(wr + 8 * qd),
                           *(const float4*)(wr + 8 * qd + 4));
    const f16x8 A1 = pack8(*(const float4*)(wr + 32 + 8 * qd),
                           *(const float4*)(wr + 32 + 8 * qd + 4));
    const float4 bias = *(const float4*)(L2b + 16 * wv + 4 * qd);
    unsigned pk[2][4];
    #pragma unroll
    for (int ss = 0; ss < 2; ++ss) {
      const unsigned* sAtp = (const unsigned*)(smem + ss * 1152);
      #pragma unroll
      for (int nt = 0; nt < 2; ++nt) {
        const int n = nt * 16 + ln;
        const f16x8 B0 = __builtin_bit_cast(f16x8, *(const int4*)(sAtp + n * 36 + 4 * qd));
        const f16x8 B1 = __builtin_bit_cast(f16x8, *(const int4*)(sAtp + n * 36 + 16 + 4 * qd));
        f32x4 c; c[0] = bias.x; c[1] = bias.y; c[2] = bias.z; c[3] = bias.w;
        c = __builtin_amdgcn_mfma_f32_16x16x32_f16(A0, B0, c, 0, 0, 0);
        c = __builtin_amdgcn_mfma_f32_16x16x32_f16(A1, B1, c, 0, 0, 0);
        pk[ss][nt * 2]     = pbits(pack2(fmaxf(c[0], 0.f), fmaxf(c[1], 0.f)));
        pk[ss][nt * 2 + 1] = pbits(pack2(fmaxf(c[2], 0.f), fmaxf(c[3], 0.f)));
      }
    }
    __syncthreads();   // all sAtp reads done before overwrite
    #pragma unroll
    for (int ss = 0; ss < 2; ++ss) {
      unsigned* sBtp = (unsigned*)(smem + ss * 1152);
      #pragma unroll
      for (int nt = 0; nt < 2; ++nt) {
        const int n = nt * 16 + ln;
        sBtp[n * 36 + 8 * wv + 2 * qd]     = pk[ss][nt * 2];
        sBtp[n * 36 + 8 * wv + 2 * qd + 1] = pk[ss][nt * 2 + 1];
      }
    }
  }
  __syncthreads();

  // ---- phase 3: g = h2 @ I1W^T via MFMA; store E = exp2(g') only ----
  {
    const int m = 16 * wv + ln;
    const float* wr = I1W + m * HID;
    const f16x8 A0 = pack8(*(const float4*)(wr + 8 * qd),
                           *(const float4*)(wr + 8 * qd + 4));
    const f16x8 A1 = pack8(*(const float4*)(wr + 32 + 8 * qd),
                           *(const float4*)(wr + 32 + 8 * qd + 4));
    #pragma unroll
    for (int ss = 0; ss < 2; ++ss) {
      const unsigned* sBtp = (const unsigned*)(smem + ss * 1152);
      float* sE = sE0 + ss * 2176;
      #pragma unroll
      for (int nt = 0; nt < 2; ++nt) {
        const int n = nt * 16 + ln;
        const f16x8 B0 = __builtin_bit_cast(f16x8, *(const int4*)(sBtp + n * 36 + 4 * qd));
        const f16x8 B1 = __builtin_bit_cast(f16x8, *(const int4*)(sBtp + n * 36 + 16 + 4 * qd));
        f32x4 c; c[0] = 0.f; c[1] = 0.f; c[2] = 0.f; c[3] = 0.f;
        c = __builtin_amdgcn_mfma_f32_16x16x32_f16(A0, B0, c, 0, 0, 0);
        c = __builtin_amdgcn_mfma_f32_16x16x32_f16(A1, B1, c, 0, 0, 0);
        #pragma unroll
        for (int r = 0; r < 4; ++r) {
          const int mo = 16 * wv + 4 * qd + r;
          float gp = fminf(fmaxf(c[r] * TWO_LOG2E, -60.0f), 60.0f);
          sE[n * 68 + mo] = EXP2F(gp);
        }
      }
    }
  }
  __syncthreads();   // region A + sE settled before 4a

  // ---- phase 4a: pair dots via MFMA, both ss per tile. r = Ej*rcp(Ei+Ej);
  // u = W - 2c; v = tanh(u) -> sv(ss)[p][f], lanes ln<8. ----
  {
    const f16x8 B0 = __builtin_bit_cast(f16x8, *(const int4*)(wB + ln * 32 + 4 * qd));
    const f16x8 B1 = __builtin_bit_cast(f16x8, *(const int4*)(wB + ln * 32 + 16 + 4 * qd));
    const float Wf = sW[ln & 7];

    for (int tile = wv; tile < NTILE; tile += 4) {
      const unsigned pij = ptab[tile * 16 + ln];   // shared across ss
      const int i = pij >> 8, j = pij & 255;
      #pragma unroll
      for (int ss = 0; ss < 2; ++ss) {
        const float* sE = sE0 + ss * 2176;
        _Float16* sv = ss ? (_Float16*)(smem + 6656) : (_Float16*)smem;
        const float* Ei = sE + i * 68 + qd * 8;
        const float* Ej = sE + j * 68 + qd * 8;
        const float4 e0 = *(const float4*)(Ei);
        const float4 e1 = *(const float4*)(Ei + 4);
        const float4 e2 = *(const float4*)(Ei + 32);
        const float4 e3 = *(const float4*)(Ei + 36);
        const float4 f0 = *(const float4*)(Ej);
        const float4 f1 = *(const float4*)(Ej + 4);
        const float4 f2 = *(const float4*)(Ej + 32);
        const float4 f3 = *(const float4*)(Ej + 36);
        float r0[8], r1[8];
        #pragma unroll
        for (int c = 0; c < 4; ++c) {
          r0[c]     = (&f0.x)[c] * __builtin_amdgcn_rcpf((&e0.x)[c] + (&f0.x)[c]);
          r0[4 + c] = (&f1.x)[c] * __builtin_amdgcn_rcpf((&e1.x)[c] + (&f1.x)[c]);
          r1[c]     = (&f2.x)[c] * __builtin_amdgcn_rcpf((&e2.x)[c] + (&f2.x)[c]);
          r1[4 + c] = (&f3.x)[c] * __builtin_amdgcn_rcpf((&e3.x)[c] + (&f3.x)[c]);
        }
        const f16x8 A0 = pack8f(r0);
        const f16x8 A1 = pack8f(r1);
        f32x4 c; c[0] = 0.f; c[1] = 0.f; c[2] = 0.f; c[3] = 0.f;
        c = __builtin_amdgcn_mfma_f32_16x16x32_f16(A0, B0, c, 0, 0, 0);
        c = __builtin_amdgcn_mfma_f32_16x16x32_f16(A1, B1, c, 0, 0, 0);
        if (ln < IFEAT) {
          #pragma unroll
          for (int r = 0; r < 4; ++r) {
            const float v = tanh_u(fmaf(-2.0f, c[r], Wf));
            sv[(tile * 16 + 4 * qd + r) * 8 + ln] = (_Float16)v;
          }
        }
      }
    }
  }
  __syncthreads();   // sv complete; wB dead -> part may overwrite

  // ---- phase 4b: thread = (ss, i, d, half); 15-16 partners each ----
  {
    const int ss = t >> 7, i = (t >> 2) & 31, d = (t >> 1) & 1, half = t & 1;
    const _Float16* sv = ss ? (const _Float16*)(smem + 6656) : (const _Float16*)smem;
    const int msta = half * 16;
    const int mend = half ? 31 : 16;
    float sum = 0.0f;
    for (int m = msta; m < mend; ++m) {
      const int j = m + (m >= i);
      int q; float sgn;
      if (j > i) { q = pair_cum(i) + (j - i - 1); sgn =  1.0f; }
      else       { q = pair_cum(j) + (i - j - 1); sgn = -1.0f; }
      const h2* vp = (const h2*)(sv + q * 8 + d * 4);
      const h2 va = vp[0], vb = vp[1];
      const float4 cf = *(const float4*)(I3 + (i * 31 + m) * 8 + d * 4);
      float dot;
      dot = cf.x * (float)va.x;
      dot = fmaf(cf.y, (float)va.y, dot);
      dot = fmaf(cf.z, (float)vb.x, dot);
      dot = fmaf(cf.w, (float)vb.y, dot);
      sum = fmaf(sgn, dot, sum);
    }
    part[t] = sum;
  }
  __syncthreads();

  // ---- final: combine partials + self term + store (2 s x 64 outputs) ----
  if (t < 128) {
    const int ss = t >> 6, i = (t >> 1) & 31, d = t & 1;
    const int pbase = ss * 128 + i * 4 + d * 2;
    float sum = part[pbase] + part[pbase + 1];

    float res = S2b[i * 2 + d] + sum;
    const float* xv = sx + ss * 128 + i * 4;
    #pragma unroll
    for (int k = 0; k < 2; ++k) {
      const int f = d * 2 + k;
      float hs = S1b[f];
      hs = fmaf(xv[0], S1W[f * 4 + 0], hs);
      hs = fmaf(xv[1], S1W[f * 4 + 1], hs);
      hs = fmaf(xv[2], S1W[f * 4 + 2], hs);
      hs = fmaf(xv[3], S1W[f * 4 + 3], hs);
      hs = fmaxf(hs, 0.0f);
      res = fmaf(hs, S2W[i * 4 + d * 2 + k], res);
    }
    out[(s0 + ss) * (NOBJ * 2) + i * 2 + d] = res;
  }
}

extern "C" void kernel_launch(void* const* d_in, const int* in_sizes, int n_in,
                              void* d_out, int out_size, void* d_ws, size_t ws_size,
                              hipStream_t stream) {
  const float* x   = (const float*)d_in[0];
  const float* L1W = (const float*)d_in[1];
  const float* L1b = (const float*)d_in[2];
  const float* L2W = (const float*)d_in[3];
  const float* L2b = (const float*)d_in[4];
  const float* I1W = (const float*)d_in[5];
  const float* I2W = (const float*)d_in[6];
  const float* I3  = (const float*)d_in[7];
  const float* S1W = (const float*)d_in[8];
  const float* S1b = (const float*)d_in[9];
  const float* S2W = (const float*)d_in[10];
  const float* S2b = (const float*)d_in[11];
  float* outp = (float*)d_out;

  magnet_fused<<<SEQ / 2, 256, 0, stream>>>(x, L1W, L1b, L2W, L2b, I1W, I2W, I3,
                                            S1W, S1b, S2W, S2b, outp);
}

// Round 14
// 117.672 us; speedup vs baseline: 1.7790x; 1.0019x over previous
//
#include <hip/hip_runtime.h>
#include <math.h>

#define SEQ   4096
#define NOBJ  32
#define IN_F  4
#define HID   64
#define IFEAT 8
#define NPAIR_HALF 496   // 32*31/2 unordered pairs; = 31 tiles * 16
#define NTILE 31

#define TWO_LOG2E 2.8853900817779268f   // 2*log2(e)

#if __has_builtin(__builtin_amdgcn_exp2f)
  #define EXP2F(x) __builtin_amdgcn_exp2f(x)
#else
  #define EXP2F(x) exp2f(x)
#endif

typedef _Float16 h2    __attribute__((ext_vector_type(2)));
typedef _Float16 f16x8 __attribute__((ext_vector_type(8)));
typedef float    f32x4 __attribute__((ext_vector_type(4)));

__device__ __forceinline__ h2 pack2(float a, float b) {
  return __builtin_bit_cast(h2, __builtin_amdgcn_cvt_pkrtz(a, b));
}
__device__ __forceinline__ unsigned pbits(h2 v) { return __builtin_bit_cast(unsigned, v); }

__device__ __forceinline__ f16x8 pack8(float4 a, float4 b) {
  int4 v;
  v.x = (int)pbits(pack2(a.x, a.y));
  v.y = (int)pbits(pack2(a.z, a.w));
  v.z = (int)pbits(pack2(b.x, b.y));
  v.w = (int)pbits(pack2(b.z, b.w));
  return __builtin_bit_cast(f16x8, v);
}

__device__ __forceinline__ f16x8 pack8f(const float* r) {
  int4 v;
  v.x = (int)pbits(pack2(r[0], r[1]));
  v.y = (int)pbits(pack2(r[2], r[3]));
  v.z = (int)pbits(pack2(r[4], r[5]));
  v.w = (int)pbits(pack2(r[6], r[7]));
  return __builtin_bit_cast(f16x8, v);
}

// tanh via exp2: tanh(x) = 1 - 2/(exp2(x*2log2e)+1)
__device__ __forceinline__ float tanh_u(float x) {
  float e = EXP2F(x * TWO_LOG2E);
  float r = __builtin_amdgcn_rcpf(e + 1.0f);
  return fmaf(-2.0f, r, 1.0f);
}

// cumulative pair count before row i (i<j ordering): C(i) = i*(63-i)/2
__device__ __forceinline__ int pair_cum(int i) { return (i * (63 - i)) >> 1; }

__device__ __forceinline__ void pair_decode(int q, int& i, int& j) {
  int ii = (int)((63.0f - sqrtf(3969.0f - 8.0f * (float)q)) * 0.5f);
  if (ii > 0 && pair_cum(ii) > q) --ii;   // fp rounding fixups
  if (pair_cum(ii + 1) <= q)     ++ii;
  i = ii;
  j = ii + 1 + (q - pair_cum(ii));
}

// 2 sequence positions per block (R12). (256,4): VGPR cap 128.
__global__ __launch_bounds__(256, 4) void magnet_fused(
    const float* __restrict__ x,      // [S,32,4]
    const float* __restrict__ L1W,    // [64,4]
    const float* __restrict__ L1b,    // [64]
    const float* __restrict__ L2W,    // [64,64]
    const float* __restrict__ L2b,    // [64]
    const float* __restrict__ I1W,    // [64,64]
    const float* __restrict__ I2W,    // [8,64]
    const float* __restrict__ I3,     // [992,2,4]
    const float* __restrict__ S1W,    // [4,4]
    const float* __restrict__ S1b,    // [4]
    const float* __restrict__ S2W,    // [32,2,2]
    const float* __restrict__ S2b,    // [32,2]
    float* __restrict__ out)          // [S,32,2]
{
  // LDS layout (float units), 9728 floats = 38912 B (see R12):
  //   [0,1152) A s0; [1152,2304) A s1; [0,1984) sv s0 (aliases A s0+s1)
  //   [2304,4480) sE s0; [4480,6656) sE s1; [6656,8640) sv s1
  //   [8640,9152) wB / part; [9152,9408) sx; [9408,9416) sW
  //   [9416,9664) ptab; [9664,9728) swpart
  __shared__ __align__(16) float smem[9728];
  float*          sE0  = smem + 2304;
  unsigned*       wB   = (unsigned*)(smem + 8640);  // [16][32]
  float*          part = smem + 8640;               // [256] (aliases wB)
  float*          sx   = smem + 9152;               // [2][32][4]
  float*          sW   = smem + 9408;               // [8]
  unsigned short* ptab = (unsigned short*)(smem + 9416); // [496]
  float*          swpart = smem + 9664;             // [64]

  const int t  = threadIdx.x;
  const int s0 = blockIdx.x * 2;

  // ---- init ----
  sx[t] = x[s0 * 128 + t];                     // 256 floats = 2 seq positions
  if (t < 64) {                                // sW partials (distributed)
    const int f = t >> 3, seg = t & 7;
    const float4 a = *(const float4*)(I2W + f * HID + seg * 8);
    const float4 b = *(const float4*)(I2W + f * HID + seg * 8 + 4);
    swpart[t] = ((a.x + a.y) + (a.z + a.w)) + ((b.x + b.y) + (b.z + b.w));
  }
  #pragma unroll
  for (int idx = t; idx < 512; idx += 256) {   // wB[n][k2]; rows 8-15 zero
    const int n = idx >> 5, k2 = idx & 31;
    wB[idx] = (n < IFEAT)
      ? pbits(pack2(I2W[n * HID + 2 * k2], I2W[n * HID + 2 * k2 + 1])) : 0u;
  }
  #pragma unroll
  for (int q = t; q < NPAIR_HALF; q += 256) {  // pair table (kills 4a decode)
    int i, j; pair_decode(q, i, j);
    ptab[q] = (unsigned short)((i << 8) | j);
  }
  __syncthreads();
  if (t < IFEAT) {                             // combine sW partials
    float a = 0.0f;
    #pragma unroll
    for (int c = 0; c < 8; ++c) a += swpart[t * 8 + c];
    sW[t] = a;                                 // read in 4a (barriers cover)
  }

  // ---- phase 1: h1 = relu(x @ L1W^T + L1b), pack f16 -> sAtp(ss)[n][k2] ----
  {
    const int n = t & 31, gI = t >> 5, kb = gI * 8;
    float a[2][8];
    #pragma unroll
    for (int r = 0; r < 8; ++r) {
      const int k = kb + r;
      const float4 w = *(const float4*)(L1W + k * 4);   // shared across ss
      const float bias = L1b[k];
      #pragma unroll
      for (int ss = 0; ss < 2; ++ss) {
        const float* xv = sx + ss * 128 + n * 4;
        float v = bias;
        v = fmaf(xv[0], w.x, v); v = fmaf(xv[1], w.y, v);
        v = fmaf(xv[2], w.z, v); v = fmaf(xv[3], w.w, v);
        a[ss][r] = fmaxf(v, 0.0f);
      }
    }
    #pragma unroll
    for (int ss = 0; ss < 2; ++ss) {
      unsigned* sAtp = (unsigned*)(smem + ss * 1152);
      int4 pk;
      pk.x = (int)pbits(pack2(a[ss][0], a[ss][1]));
      pk.y = (int)pbits(pack2(a[ss][2], a[ss][3]));
      pk.z = (int)pbits(pack2(a[ss][4], a[ss][5]));
      pk.w = (int)pbits(pack2(a[ss][6], a[ss][7]));
      *(int4*)(sAtp + n * 36 + gI * 4) = pk;
    }
  }
  __syncthreads();

  const int lane = t & 63;
  const int wv   = t >> 6;        // wave id
  const int qd   = lane >> 4;     // quad 0..3
  const int ln   = lane & 15;

  // ---- phase 2: h2 = relu(h1 @ L2W^T + L2b) via MFMA; reg-buffer both ss,
  // then overwrite region A as sBtp(ss)[n][k2]. A-frags shared across ss. ----
  {
    const int m = 16 * wv + ln;
    const float* wr = L2W + m * HID;
    const f16x8 A0 = pack8(*(const float4*)(wr + 8 * qd),
                           *(const float4*)(wr + 8 * qd + 4));
    const f16x8 A1 = pack8(*(const float4*)(wr + 32 + 8 * qd),
                           *(const float4*)(wr + 32 + 8 * qd + 4));
    const float4 bias = *(const float4*)(L2b + 16 * wv + 4 * qd);
    unsigned pk[2][4];
    #pragma unroll
    for (int ss = 0; ss < 2; ++ss) {
      const unsigned* sAtp = (const unsigned*)(smem + ss * 1152);
      #pragma unroll
      for (int nt = 0; nt < 2; ++nt) {
        const int n = nt * 16 + ln;
        const f16x8 B0 = __builtin_bit_cast(f16x8, *(const int4*)(sAtp + n * 36 + 4 * qd));
        const f16x8 B1 = __builtin_bit_cast(f16x8, *(const int4*)(sAtp + n * 36 + 16 + 4 * qd));
        f32x4 c; c[0] = bias.x; c[1] = bias.y; c[2] = bias.z; c[3] = bias.w;
        c = __builtin_amdgcn_mfma_f32_16x16x32_f16(A0, B0, c, 0, 0, 0);
        c = __builtin_amdgcn_mfma_f32_16x16x32_f16(A1, B1, c, 0, 0, 0);
        pk[ss][nt * 2]     = pbits(pack2(fmaxf(c[0], 0.f), fmaxf(c[1], 0.f)));
        pk[ss][nt * 2 + 1] = pbits(pack2(fmaxf(c[2], 0.f), fmaxf(c[3], 0.f)));
      }
    }
    __syncthreads();   // all sAtp reads done before overwrite
    #pragma unroll
    for (int ss = 0; ss < 2; ++ss) {
      unsigned* sBtp = (unsigned*)(smem + ss * 1152);
      #pragma unroll
      for (int nt = 0; nt < 2; ++nt) {
        const int n = nt * 16 + ln;
        sBtp[n * 36 + 8 * wv + 2 * qd]     = pk[ss][nt * 2];
        sBtp[n * 36 + 8 * wv + 2 * qd + 1] = pk[ss][nt * 2 + 1];
      }
    }
  }
  __syncthreads();

  // ---- phase 3: g = h2 @ I1W^T via MFMA; store E = exp2(g') only ----
  {
    const int m = 16 * wv + ln;
    const float* wr = I1W + m * HID;
    const f16x8 A0 = pack8(*(const float4*)(wr + 8 * qd),
                           *(const float4*)(wr + 8 * qd + 4));
    const f16x8 A1 = pack8(*(const float4*)(wr + 32 + 8 * qd),
                           *(const float4*)(wr + 32 + 8 * qd + 4));
    #pragma unroll
    for (int ss = 0; ss < 2; ++ss) {
      const unsigned* sBtp = (const unsigned*)(smem + ss * 1152);
      float* sE = sE0 + ss * 2176;
      #pragma unroll
      for (int nt = 0; nt < 2; ++nt) {
        const int n = nt * 16 + ln;
        const f16x8 B0 = __builtin_bit_cast(f16x8, *(const int4*)(sBtp + n * 36 + 4 * qd));
        const f16x8 B1 = __builtin_bit_cast(f16x8, *(const int4*)(sBtp + n * 36 + 16 + 4 * qd));
        f32x4 c; c[0] = 0.f; c[1] = 0.f; c[2] = 0.f; c[3] = 0.f;
        c = __builtin_amdgcn_mfma_f32_16x16x32_f16(A0, B0, c, 0, 0, 0);
        c = __builtin_amdgcn_mfma_f32_16x16x32_f16(A1, B1, c, 0, 0, 0);
        #pragma unroll
        for (int r = 0; r < 4; ++r) {
          const int mo = 16 * wv + 4 * qd + r;
          float gp = fminf(fmaxf(c[r] * TWO_LOG2E, -60.0f), 60.0f);
          sE[n * 68 + mo] = EXP2F(gp);
        }
      }
    }
  }
  __syncthreads();   // region A + sE settled before 4a

  // ---- phase 4a: pair dots via MFMA, both ss per tile.
  // Batch inversion (1 rcp per 2 elems): q=rcp(a*b), r0=(f0*b)*q, r1=(f1*a)*q
  // (a*b <= 2^122 < f32 max). Epilogue merged across ss via lane-split shfl:
  // lanes 0-7 apply tanh for ss0, lanes 8-15 for ss1 (trans cost is
  // per-instruction, so the old per-ss half-idle epilogue paid 2x). ----
  {
    const f16x8 B0 = __builtin_bit_cast(f16x8, *(const int4*)(wB + ln * 32 + 4 * qd));
    const f16x8 B1 = __builtin_bit_cast(f16x8, *(const int4*)(wB + ln * 32 + 16 + 4 * qd));
    const float Wf = sW[ln & 7];
    _Float16* svp = (ln < IFEAT) ? (_Float16*)smem : (_Float16*)(smem + 6656);
    const int srcl = lane - ((ln >= IFEAT) ? IFEAT : 0);

    for (int tile = wv; tile < NTILE; tile += 4) {
      const unsigned pij = ptab[tile * 16 + ln];   // shared across ss
      const int i = pij >> 8, j = pij & 255;
      f32x4 cs[2];
      #pragma unroll
      for (int ss = 0; ss < 2; ++ss) {
        const float* sE = sE0 + ss * 2176;
        const float* Ei = sE + i * 68 + qd * 8;
        const float* Ej = sE + j * 68 + qd * 8;
        const float4 e0 = *(const float4*)(Ei);
        const float4 e1 = *(const float4*)(Ei + 4);
        const float4 e2 = *(const float4*)(Ei + 32);
        const float4 e3 = *(const float4*)(Ei + 36);
        const float4 f0 = *(const float4*)(Ej);
        const float4 f1 = *(const float4*)(Ej + 4);
        const float4 f2 = *(const float4*)(Ej + 32);
        const float4 f3 = *(const float4*)(Ej + 36);
        float r0[8], r1[8];
        #pragma unroll
        for (int c = 0; c < 4; ++c) {
          const float a0 = (&e0.x)[c] + (&f0.x)[c];
          const float b0 = (&e1.x)[c] + (&f1.x)[c];
          const float q0 = __builtin_amdgcn_rcpf(a0 * b0);
          r0[c]     = ((&f0.x)[c] * b0) * q0;
          r0[4 + c] = ((&f1.x)[c] * a0) * q0;
          const float a1 = (&e2.x)[c] + (&f2.x)[c];
          const float b1 = (&e3.x)[c] + (&f3.x)[c];
          const float q1 = __builtin_amdgcn_rcpf(a1 * b1);
          r1[c]     = ((&f2.x)[c] * b1) * q1;
          r1[4 + c] = ((&f3.x)[c] * a1) * q1;
        }
        const f16x8 A0 = pack8f(r0);
        const f16x8 A1 = pack8f(r1);
        f32x4 c; c[0] = 0.f; c[1] = 0.f; c[2] = 0.f; c[3] = 0.f;
        c = __builtin_amdgcn_mfma_f32_16x16x32_f16(A0, B0, c, 0, 0, 0);
        cs[ss] = __builtin_amdgcn_mfma_f32_16x16x32_f16(A1, B1, c, 0, 0, 0);
      }
      // merged epilogue: lane f<8 -> ss0 col f; lane 8+f -> ss1 col f (shfl)
      #pragma unroll
      for (int r = 0; r < 4; ++r) {
        const float c1 = __shfl(cs[1][r], srcl, 64);
        const float cc = (ln < IFEAT) ? cs[0][r] : c1;
        const float v  = tanh_u(fmaf(-2.0f, cc, Wf));
        svp[(tile * 16 + 4 * qd + r) * 8 + (ln & 7)] = (_Float16)v;
      }
    }
  }
  __syncthreads();   // sv complete; wB dead -> part may overwrite

  // ---- phase 4b: thread = (ss, i, d, half); 15-16 partners each ----
  {
    const int ss = t >> 7, i = (t >> 2) & 31, d = (t >> 1) & 1, half = t & 1;
    const _Float16* sv = ss ? (const _Float16*)(smem + 6656) : (const _Float16*)smem;
    const int msta = half * 16;
    const int mend = half ? 31 : 16;
    float sum = 0.0f;
    for (int m = msta; m < mend; ++m) {
      const int j = m + (m >= i);
      int q; float sgn;
      if (j > i) { q = pair_cum(i) + (j - i - 1); sgn =  1.0f; }
      else       { q = pair_cum(j) + (i - j - 1); sgn = -1.0f; }
      const h2* vp = (const h2*)(sv + q * 8 + d * 4);
      const h2 va = vp[0], vb = vp[1];
      const float4 cf = *(const float4*)(I3 + (i * 31 + m) * 8 + d * 4);
      float dot;
      dot = cf.x * (float)va.x;
      dot = fmaf(cf.y, (float)va.y, dot);
      dot = fmaf(cf.z, (float)vb.x, dot);
      dot = fmaf(cf.w, (float)vb.y, dot);
      sum = fmaf(sgn, dot, sum);
    }
    part[t] = sum;
  }
  __syncthreads();

  // ---- final: combine partials + self term + store (2 s x 64 outputs) ----
  if (t < 128) {
    const int ss = t >> 6, i = (t >> 1) & 31, d = t & 1;
    const int pbase = ss * 128 + i * 4 + d * 2;
    float sum = part[pbase] + part[pbase + 1];

    float res = S2b[i * 2 + d] + sum;
    const float* xv = sx + ss * 128 + i * 4;
    #pragma unroll
    for (int k = 0; k < 2; ++k) {
      const int f = d * 2 + k;
      float hs = S1b[f];
      hs = fmaf(xv[0], S1W[f * 4 + 0], hs);
      hs = fmaf(xv[1], S1W[f * 4 + 1], hs);
      hs = fmaf(xv[2], S1W[f * 4 + 2], hs);
      hs = fmaf(xv[3], S1W[f * 4 + 3], hs);
      hs = fmaxf(hs, 0.0f);
      res = fmaf(hs, S2W[i * 4 + d * 2 + k], res);
    }
    out[(s0 + ss) * (NOBJ * 2) + i * 2 + d] = res;
  }
}

extern "C" void kernel_launch(void* const* d_in, const int* in_sizes, int n_in,
                              void* d_out, int out_size, void* d_ws, size_t ws_size,
                              hipStream_t stream) {
  const float* x   = (const float*)d_in[0];
  const float* L1W = (const float*)d_in[1];
  const float* L1b = (const float*)d_in[2];
  const float* L2W = (const float*)d_in[3];
  const float* L2b = (const float*)d_in[4];
  const float* I1W = (const float*)d_in[5];
  const float* I2W = (const float*)d_in[6];
  const float* I3  = (const float*)d_in[7];
  const float* S1W = (const float*)d_in[8];
  const float* S1b = (const float*)d_in[9];
  const float* S2W = (const float*)d_in[10];
  const float* S2b = (const float*)d_in[11];
  float* outp = (float*)d_out;

  magnet_fused<<<SEQ / 2, 256, 0, stream>>>(x, L1W, L1b, L2W, L2b, I1W, I2W, I3,
                                            S1W, S1b, S2W, S2b, outp);
}

// Round 15
// 116.532 us; speedup vs baseline: 1.7964x; 1.0098x over previous
//
#include <hip/hip_runtime.h>
#include <math.h>

#define SEQ   4096
#define NOBJ  32
#define IN_F  4
#define HID   64
#define IFEAT 8
#define NPAIR_HALF 496   // 32*31/2 unordered pairs; = 31 tiles * 16
#define NTILE 31

#define TWO_LOG2E 2.8853900817779268f   // 2*log2(e)
#define GP_CLAMP  10.0f                 // E=exp2(g') in [2^-10,2^10]: f16-safe

#if __has_builtin(__builtin_amdgcn_exp2f)
  #define EXP2F(x) __builtin_amdgcn_exp2f(x)
#else
  #define EXP2F(x) exp2f(x)
#endif

#if __has_builtin(__builtin_amdgcn_rcph)
  #define RCPH(x) __builtin_amdgcn_rcph(x)
#else
  #define RCPH(x) ((_Float16)__builtin_amdgcn_rcpf((float)(x)))
#endif

typedef _Float16 h2    __attribute__((ext_vector_type(2)));
typedef _Float16 f16x8 __attribute__((ext_vector_type(8)));
typedef float    f32x4 __attribute__((ext_vector_type(4)));

__device__ __forceinline__ h2 pack2(float a, float b) {
  return __builtin_bit_cast(h2, __builtin_amdgcn_cvt_pkrtz(a, b));
}
__device__ __forceinline__ unsigned pbits(h2 v) { return __builtin_bit_cast(unsigned, v); }

__device__ __forceinline__ f16x8 pack8(float4 a, float4 b) {
  int4 v;
  v.x = (int)pbits(pack2(a.x, a.y));
  v.y = (int)pbits(pack2(a.z, a.w));
  v.z = (int)pbits(pack2(b.x, b.y));
  v.w = (int)pbits(pack2(b.z, b.w));
  return __builtin_bit_cast(f16x8, v);
}

// tanh via exp2: tanh(x) = 1 - 2/(exp2(x*2log2e)+1)
__device__ __forceinline__ float tanh_u(float x) {
  float e = EXP2F(x * TWO_LOG2E);
  float r = __builtin_amdgcn_rcpf(e + 1.0f);
  return fmaf(-2.0f, r, 1.0f);
}

// cumulative pair count before row i (i<j ordering): C(i) = i*(63-i)/2
__device__ __forceinline__ int pair_cum(int i) { return (i * (63 - i)) >> 1; }

__device__ __forceinline__ void pair_decode(int q, int& i, int& j) {
  int ii = (int)((63.0f - sqrtf(3969.0f - 8.0f * (float)q)) * 0.5f);
  if (ii > 0 && pair_cum(ii) > q) --ii;   // fp rounding fixups
  if (pair_cum(ii + 1) <= q)     ++ii;
  i = ii;
  j = ii + 1 + (q - pair_cum(ii));
}

// 2 sequence positions per block (R12). (256,4): VGPR cap 128.
__global__ __launch_bounds__(256, 4) void magnet_fused(
    const float* __restrict__ x,      // [S,32,4]
    const float* __restrict__ L1W,    // [64,4]
    const float* __restrict__ L1b,    // [64]
    const float* __restrict__ L2W,    // [64,64]
    const float* __restrict__ L2b,    // [64]
    const float* __restrict__ I1W,    // [64,64]
    const float* __restrict__ I2W,    // [8,64]
    const float* __restrict__ I3,     // [992,2,4]
    const float* __restrict__ S1W,    // [4,4]
    const float* __restrict__ S1b,    // [4]
    const float* __restrict__ S2W,    // [32,2,2]
    const float* __restrict__ S2b,    // [32,2]
    float* __restrict__ out)          // [S,32,2]
{
  // LDS layout (float units), 7680 floats = 30720 B -> 5 blocks/CU:
  //   [0,1152)     A s0: sAtp/sBtp s0 (barriered alias)
  //   [1152,2304)  A s1
  //   [0,1984)     sv s0 (ph4a-4b; aliases A s0+s1, both dead after ph3)
  //   [2304,3456)  sE s0: f16[32][72] (36-dword rows; E = exp2(g') f16)
  //   [3456,4608)  sE s1
  //   [4608,6592)  sv s1 (dedicated, 1984 floats)
  //   [6592,7104)  wB [16][32] uint I2W B-frags / part[256] (4b alias)
  //   [7104,7360)  sx [2][32][4]
  //   [7360,7368)  sW [8]
  //   [7368,7616)  ptab [496] u16 (i<<8|j)
  //   [7616,7680)  swpart [64]
  __shared__ __align__(16) float smem[7680];
  unsigned*       sEd0 = (unsigned*)(smem + 2304);  // dword view of f16 E
  unsigned*       wB   = (unsigned*)(smem + 6592);  // [16][32]
  float*          part = smem + 6592;               // [256] (aliases wB)
  float*          sx   = smem + 7104;               // [2][32][4]
  float*          sW   = smem + 7360;               // [8]
  unsigned short* ptab = (unsigned short*)(smem + 7368); // [496]
  float*          swpart = smem + 7616;             // [64]

  const int t  = threadIdx.x;
  const int s0 = blockIdx.x * 2;

  // ---- init ----
  sx[t] = x[s0 * 128 + t];                     // 256 floats = 2 seq positions
  if (t < 64) {                                // sW partials (distributed)
    const int f = t >> 3, seg = t & 7;
    const float4 a = *(const float4*)(I2W + f * HID + seg * 8);
    const float4 b = *(const float4*)(I2W + f * HID + seg * 8 + 4);
    swpart[t] = ((a.x + a.y) + (a.z + a.w)) + ((b.x + b.y) + (b.z + b.w));
  }
  #pragma unroll
  for (int idx = t; idx < 512; idx += 256) {   // wB[n][k2]; rows 8-15 zero
    const int n = idx >> 5, k2 = idx & 31;
    wB[idx] = (n < IFEAT)
      ? pbits(pack2(I2W[n * HID + 2 * k2], I2W[n * HID + 2 * k2 + 1])) : 0u;
  }
  #pragma unroll
  for (int q = t; q < NPAIR_HALF; q += 256) {  // pair table (kills 4a decode)
    int i, j; pair_decode(q, i, j);
    ptab[q] = (unsigned short)((i << 8) | j);
  }
  __syncthreads();
  if (t < IFEAT) {                             // combine sW partials
    float a = 0.0f;
    #pragma unroll
    for (int c = 0; c < 8; ++c) a += swpart[t * 8 + c];
    sW[t] = a;                                 // read in 4a (barriers cover)
  }

  // ---- phase 1: h1 = relu(x @ L1W^T + L1b), pack f16 -> sAtp(ss)[n][k2] ----
  {
    const int n = t & 31, gI = t >> 5, kb = gI * 8;
    float a[2][8];
    #pragma unroll
    for (int r = 0; r < 8; ++r) {
      const int k = kb + r;
      const float4 w = *(const float4*)(L1W + k * 4);   // shared across ss
      const float bias = L1b[k];
      #pragma unroll
      for (int ss = 0; ss < 2; ++ss) {
        const float* xv = sx + ss * 128 + n * 4;
        float v = bias;
        v = fmaf(xv[0], w.x, v); v = fmaf(xv[1], w.y, v);
        v = fmaf(xv[2], w.z, v); v = fmaf(xv[3], w.w, v);
        a[ss][r] = fmaxf(v, 0.0f);
      }
    }
    #pragma unroll
    for (int ss = 0; ss < 2; ++ss) {
      unsigned* sAtp = (unsigned*)(smem + ss * 1152);
      int4 pk;
      pk.x = (int)pbits(pack2(a[ss][0], a[ss][1]));
      pk.y = (int)pbits(pack2(a[ss][2], a[ss][3]));
      pk.z = (int)pbits(pack2(a[ss][4], a[ss][5]));
      pk.w = (int)pbits(pack2(a[ss][6], a[ss][7]));
      *(int4*)(sAtp + n * 36 + gI * 4) = pk;
    }
  }
  __syncthreads();

  const int lane = t & 63;
  const int wv   = t >> 6;        // wave id
  const int qd   = lane >> 4;     // quad 0..3
  const int ln   = lane & 15;

  // ---- phase 2: h2 = relu(h1 @ L2W^T + L2b) via MFMA; reg-buffer both ss,
  // then overwrite region A as sBtp(ss)[n][k2]. A-frags shared across ss. ----
  {
    const int m = 16 * wv + ln;
    const float* wr = L2W + m * HID;
    const f16x8 A0 = pack8(*(const float4*)(wr + 8 * qd),
                           *(const float4*)(wr + 8 * qd + 4));
    const f16x8 A1 = pack8(*(const float4*)(wr + 32 + 8 * qd),
                           *(const float4*)(wr + 32 + 8 * qd + 4));
    const float4 bias = *(const float4*)(L2b + 16 * wv + 4 * qd);
    unsigned pk[2][4];
    #pragma unroll
    for (int ss = 0; ss < 2; ++ss) {
      const unsigned* sAtp = (const unsigned*)(smem + ss * 1152);
      #pragma unroll
      for (int nt = 0; nt < 2; ++nt) {
        const int n = nt * 16 + ln;
        const f16x8 B0 = __builtin_bit_cast(f16x8, *(const int4*)(sAtp + n * 36 + 4 * qd));
        const f16x8 B1 = __builtin_bit_cast(f16x8, *(const int4*)(sAtp + n * 36 + 16 + 4 * qd));
        f32x4 c; c[0] = bias.x; c[1] = bias.y; c[2] = bias.z; c[3] = bias.w;
        c = __builtin_amdgcn_mfma_f32_16x16x32_f16(A0, B0, c, 0, 0, 0);
        c = __builtin_amdgcn_mfma_f32_16x16x32_f16(A1, B1, c, 0, 0, 0);
        pk[ss][nt * 2]     = pbits(pack2(fmaxf(c[0], 0.f), fmaxf(c[1], 0.f)));
        pk[ss][nt * 2 + 1] = pbits(pack2(fmaxf(c[2], 0.f), fmaxf(c[3], 0.f)));
      }
    }
    __syncthreads();   // all sAtp reads done before overwrite
    #pragma unroll
    for (int ss = 0; ss < 2; ++ss) {
      unsigned* sBtp = (unsigned*)(smem + ss * 1152);
      #pragma unroll
      for (int nt = 0; nt < 2; ++nt) {
        const int n = nt * 16 + ln;
        sBtp[n * 36 + 8 * wv + 2 * qd]     = pk[ss][nt * 2];
        sBtp[n * 36 + 8 * wv + 2 * qd + 1] = pk[ss][nt * 2 + 1];
      }
    }
  }
  __syncthreads();

  // ---- phase 3: g = h2 @ I1W^T via MFMA; store E = exp2(g') as f16 pairs ----
  {
    const int m = 16 * wv + ln;
    const float* wr = I1W + m * HID;
    const f16x8 A0 = pack8(*(const float4*)(wr + 8 * qd),
                           *(const float4*)(wr + 8 * qd + 4));
    const f16x8 A1 = pack8(*(const float4*)(wr + 32 + 8 * qd),
                           *(const float4*)(wr + 32 + 8 * qd + 4));
    #pragma unroll
    for (int ss = 0; ss < 2; ++ss) {
      const unsigned* sBtp = (const unsigned*)(smem + ss * 1152);
      unsigned* sEd = sEd0 + ss * 1152;
      #pragma unroll
      for (int nt = 0; nt < 2; ++nt) {
        const int n = nt * 16 + ln;
        const f16x8 B0 = __builtin_bit_cast(f16x8, *(const int4*)(sBtp + n * 36 + 4 * qd));
        const f16x8 B1 = __builtin_bit_cast(f16x8, *(const int4*)(sBtp + n * 36 + 16 + 4 * qd));
        f32x4 c; c[0] = 0.f; c[1] = 0.f; c[2] = 0.f; c[3] = 0.f;
        c = __builtin_amdgcn_mfma_f32_16x16x32_f16(A0, B0, c, 0, 0, 0);
        c = __builtin_amdgcn_mfma_f32_16x16x32_f16(A1, B1, c, 0, 0, 0);
        float e[4];
        #pragma unroll
        for (int r = 0; r < 4; ++r) {
          float gp = fminf(fmaxf(c[r] * TWO_LOG2E, -GP_CLAMP), GP_CLAMP);
          e[r] = EXP2F(gp);
        }
        // mo = 16wv+4qd+r; f16 idx n*72+mo -> dword n*36 + 8wv + 2qd + {0,1}
        sEd[n * 36 + 8 * wv + 2 * qd]     = pbits(pack2(e[0], e[1]));
        sEd[n * 36 + 8 * wv + 2 * qd + 1] = pbits(pack2(e[2], e[3]));
      }
    }
  }
  __syncthreads();   // region A + sE settled before 4a

  // ---- phase 4a: pair dots via MFMA, both ss per tile. All-f16 hot path:
  // A = fj * rcph(ei + fj) (packed f16 ops, no cvt packs, half the LDS reads).
  // u = W - 2c; v = tanh(u) -> sv(ss)[p][f], lanes ln<8. ----
  {
    const f16x8 B0 = __builtin_bit_cast(f16x8, *(const int4*)(wB + ln * 32 + 4 * qd));
    const f16x8 B1 = __builtin_bit_cast(f16x8, *(const int4*)(wB + ln * 32 + 16 + 4 * qd));
    const float Wf = sW[ln & 7];

    for (int tile = wv; tile < NTILE; tile += 4) {
      const unsigned pij = ptab[tile * 16 + ln];   // shared across ss
      const int i = pij >> 8, j = pij & 255;
      #pragma unroll
      for (int ss = 0; ss < 2; ++ss) {
        const unsigned* sEd = sEd0 + ss * 1152;
        _Float16* sv = ss ? (_Float16*)(smem + 4608) : (_Float16*)smem;
        const f16x8 ei0 = __builtin_bit_cast(f16x8, *(const int4*)(sEd + i * 36 + 4 * qd));
        const f16x8 ei1 = __builtin_bit_cast(f16x8, *(const int4*)(sEd + i * 36 + 16 + 4 * qd));
        const f16x8 fj0 = __builtin_bit_cast(f16x8, *(const int4*)(sEd + j * 36 + 4 * qd));
        const f16x8 fj1 = __builtin_bit_cast(f16x8, *(const int4*)(sEd + j * 36 + 16 + 4 * qd));
        const f16x8 su0 = ei0 + fj0;               // v_pk_add_f16
        const f16x8 su1 = ei1 + fj1;
        f16x8 q0, q1;
        #pragma unroll
        for (int k = 0; k < 8; ++k) { q0[k] = RCPH(su0[k]); q1[k] = RCPH(su1[k]); }
        const f16x8 A0 = fj0 * q0;                 // v_pk_mul_f16; r in [0,1]
        const f16x8 A1 = fj1 * q1;
        f32x4 c; c[0] = 0.f; c[1] = 0.f; c[2] = 0.f; c[3] = 0.f;
        c = __builtin_amdgcn_mfma_f32_16x16x32_f16(A0, B0, c, 0, 0, 0);
        c = __builtin_amdgcn_mfma_f32_16x16x32_f16(A1, B1, c, 0, 0, 0);
        if (ln < IFEAT) {
          #pragma unroll
          for (int r = 0; r < 4; ++r) {
            const float v = tanh_u(fmaf(-2.0f, c[r], Wf));
            sv[(tile * 16 + 4 * qd + r) * 8 + ln] = (_Float16)v;
          }
        }
      }
    }
  }
  __syncthreads();   // sv complete; wB dead -> part may overwrite

  // ---- phase 4b: thread = (ss, i, d, half); 15-16 partners each ----
  {
    const int ss = t >> 7, i = (t >> 2) & 31, d = (t >> 1) & 1, half = t & 1;
    const _Float16* sv = ss ? (const _Float16*)(smem + 4608) : (const _Float16*)smem;
    const int msta = half * 16;
    const int mend = half ? 31 : 16;
    float sum = 0.0f;
    for (int m = msta; m < mend; ++m) {
      const int j = m + (m >= i);
      int q; float sgn;
      if (j > i) { q = pair_cum(i) + (j - i - 1); sgn =  1.0f; }
      else       { q = pair_cum(j) + (i - j - 1); sgn = -1.0f; }
      const h2* vp = (const h2*)(sv + q * 8 + d * 4);
      const h2 va = vp[0], vb = vp[1];
      const float4 cf = *(const float4*)(I3 + (i * 31 + m) * 8 + d * 4);
      float dot;
      dot = cf.x * (float)va.x;
      dot = fmaf(cf.y, (float)va.y, dot);
      dot = fmaf(cf.z, (float)vb.x, dot);
      dot = fmaf(cf.w, (float)vb.y, dot);
      sum = fmaf(sgn, dot, sum);
    }
    part[t] = sum;
  }
  __syncthreads();

  // ---- final: combine partials + self term + store (2 s x 64 outputs) ----
  if (t < 128) {
    const int ss = t >> 6, i = (t >> 1) & 31, d = t & 1;
    const int pbase = ss * 128 + i * 4 + d * 2;
    float sum = part[pbase] + part[pbase + 1];

    float res = S2b[i * 2 + d] + sum;
    const float* xv = sx + ss * 128 + i * 4;
    #pragma unroll
    for (int k = 0; k < 2; ++k) {
      const int f = d * 2 + k;
      float hs = S1b[f];
      hs = fmaf(xv[0], S1W[f * 4 + 0], hs);
      hs = fmaf(xv[1], S1W[f * 4 + 1], hs);
      hs = fmaf(xv[2], S1W[f * 4 + 2], hs);
      hs = fmaf(xv[3], S1W[f * 4 + 3], hs);
      hs = fmaxf(hs, 0.0f);
      res = fmaf(hs, S2W[i * 4 + d * 2 + k], res);
    }
    out[(s0 + ss) * (NOBJ * 2) + i * 2 + d] = res;
  }
}

extern "C" void kernel_launch(void* const* d_in, const int* in_sizes, int n_in,
                              void* d_out, int out_size, void* d_ws, size_t ws_size,
                              hipStream_t stream) {
  const float* x   = (const float*)d_in[0];
  const float* L1W = (const float*)d_in[1];
  const float* L1b = (const float*)d_in[2];
  const float* L2W = (const float*)d_in[3];
  const float* L2b = (const float*)d_in[4];
  const float* I1W = (const float*)d_in[5];
  const float* I2W = (const float*)d_in[6];
  const float* I3  = (const float*)d_in[7];
  const float* S1W = (const float*)d_in[8];
  const float* S1b = (const float*)d_in[9];
  const float* S2W = (const float*)d_in[10];
  const float* S2b = (const float*)d_in[11];
  float* outp = (float*)d_out;

  magnet_fused<<<SEQ / 2, 256, 0, stream>>>(x, L1W, L1b, L2W, L2b, I1W, I2W, I3,
                                            S1W, S1b, S2W, S2b, outp);
}

// Round 16
// 114.004 us; speedup vs baseline: 1.8362x; 1.0222x over previous
//
#include <hip/hip_runtime.h>
#include <math.h>

#define SEQ   4096
#define NOBJ  32
#define IN_F  4
#define HID   64
#define IFEAT 8
#define NPAIR_HALF 496   // 32*31/2 unordered pairs; = 31 tiles * 16
#define NTILE 31

#define TWO_LOG2E 2.8853900817779268f   // 2*log2(e)
#define GP_CLAMP  10.0f                 // E=exp2(g') in [2^-10,2^10]: f16-safe

#if __has_builtin(__builtin_amdgcn_exp2f)
  #define EXP2F(x) __builtin_amdgcn_exp2f(x)
#else
  #define EXP2F(x) exp2f(x)
#endif

#if __has_builtin(__builtin_amdgcn_rcph)
  #define RCPH(x) __builtin_amdgcn_rcph(x)
#else
  #define RCPH(x) ((_Float16)__builtin_amdgcn_rcpf((float)(x)))
#endif

typedef _Float16 h2    __attribute__((ext_vector_type(2)));
typedef _Float16 f16x8 __attribute__((ext_vector_type(8)));
typedef float    f32x4 __attribute__((ext_vector_type(4)));

__device__ __forceinline__ h2 pack2(float a, float b) {
  return __builtin_bit_cast(h2, __builtin_amdgcn_cvt_pkrtz(a, b));
}
__device__ __forceinline__ unsigned pbits(h2 v) { return __builtin_bit_cast(unsigned, v); }

__device__ __forceinline__ f16x8 pack8(float4 a, float4 b) {
  int4 v;
  v.x = (int)pbits(pack2(a.x, a.y));
  v.y = (int)pbits(pack2(a.z, a.w));
  v.z = (int)pbits(pack2(b.x, b.y));
  v.w = (int)pbits(pack2(b.z, b.w));
  return __builtin_bit_cast(f16x8, v);
}

// tanh via exp2: tanh(x) = 1 - 2/(exp2(x*2log2e)+1)
__device__ __forceinline__ float tanh_u(float x) {
  float e = EXP2F(x * TWO_LOG2E);
  float r = __builtin_amdgcn_rcpf(e + 1.0f);
  return fmaf(-2.0f, r, 1.0f);
}

// cumulative pair count before row i (i<j ordering): C(i) = i*(63-i)/2
__device__ __forceinline__ int pair_cum(int i) { return (i * (63 - i)) >> 1; }

__device__ __forceinline__ void pair_decode(int q, int& i, int& j) {
  int ii = (int)((63.0f - sqrtf(3969.0f - 8.0f * (float)q)) * 0.5f);
  if (ii > 0 && pair_cum(ii) > q) --ii;   // fp rounding fixups
  if (pair_cum(ii + 1) <= q)     ++ii;
  i = ii;
  j = ii + 1 + (q - pair_cum(ii));
}

// 2 sequence positions per block (R12). (256,4): VGPR cap 128.
__global__ __launch_bounds__(256, 4) void magnet_fused(
    const float* __restrict__ x,      // [S,32,4]
    const float* __restrict__ L1W,    // [64,4]
    const float* __restrict__ L1b,    // [64]
    const float* __restrict__ L2W,    // [64,64]
    const float* __restrict__ L2b,    // [64]
    const float* __restrict__ I1W,    // [64,64]
    const float* __restrict__ I2W,    // [8,64]
    const float* __restrict__ I3,     // [992,2,4]
    const float* __restrict__ S1W,    // [4,4]
    const float* __restrict__ S1b,    // [4]
    const float* __restrict__ S2W,    // [32,2,2]
    const float* __restrict__ S2b,    // [32,2]
    float* __restrict__ out)          // [S,32,2]
{
  // LDS layout (float units), 8424 floats = 33696 B -> 4 blocks/CU:
  //   [0,1152)     A s0: sAtp/sBtp s0 (barriered alias)
  //   [1152,2304)  A s1
  //   [0,1984)     sv s0 (ph4a-4b; aliases A s0+s1, both dead after ph3)
  //   [2304,3456)  sE s0: f16[32][72] (36-dword rows; E = exp2(g') f16)
  //   [3456,4608)  sE s1
  //   [4608,6592)  sv s1 (dedicated, 1984 floats)
  //   [6592,7104)  wB [16][32] uint I2W B-frags / part[256] (4b alias)
  //   [7104,7360)  sx [2][32][4]
  //   [7360,7368)  sW [8]
  //   [7368,7864)  ptab32 [496] u32: (i*36)<<16 | (j*36)  (4a row offsets)
  //   [7864,8360)  ptab2 [992] u16: q | (j<i)<<15         (4b gather table)
  //   [8360,8424)  swpart [64]
  __shared__ __align__(16) float smem[8424];
  unsigned*       sEd0 = (unsigned*)(smem + 2304);  // dword view of f16 E
  unsigned*       wB   = (unsigned*)(smem + 6592);  // [16][32]
  float*          part = smem + 6592;               // [256] (aliases wB)
  float*          sx   = smem + 7104;               // [2][32][4]
  float*          sW   = smem + 7360;               // [8]
  unsigned*       ptab32 = (unsigned*)(smem + 7368); // [496]
  unsigned short* ptab2  = (unsigned short*)(smem + 7864); // [992]
  float*          swpart = smem + 8360;             // [64]

  const int t  = threadIdx.x;
  const int s0 = blockIdx.x * 2;

  // ---- init ----
  sx[t] = x[s0 * 128 + t];                     // 256 floats = 2 seq positions
  if (t < 64) {                                // sW partials (distributed)
    const int f = t >> 3, seg = t & 7;
    const float4 a = *(const float4*)(I2W + f * HID + seg * 8);
    const float4 b = *(const float4*)(I2W + f * HID + seg * 8 + 4);
    swpart[t] = ((a.x + a.y) + (a.z + a.w)) + ((b.x + b.y) + (b.z + b.w));
  }
  #pragma unroll
  for (int idx = t; idx < 512; idx += 256) {   // wB[n][k2]; rows 8-15 zero
    const int n = idx >> 5, k2 = idx & 31;
    wB[idx] = (n < IFEAT)
      ? pbits(pack2(I2W[n * HID + 2 * k2], I2W[n * HID + 2 * k2 + 1])) : 0u;
  }
  #pragma unroll
  for (int q = t; q < NPAIR_HALF; q += 256) {  // 4a table: premult row offsets
    int i, j; pair_decode(q, i, j);
    ptab32[q] = ((unsigned)(i * 36) << 16) | (unsigned)(j * 36);
  }
  #pragma unroll
  for (int idx = t; idx < 992; idx += 256) {   // 4b table: q | sign
    const int i = (idx * 2115) >> 16;          // idx/31 (exact for idx<992)
    const int m = idx - i * 31;
    const int j = m + (m >= i);
    unsigned v;
    if (j > i) v = (unsigned)(pair_cum(i) + (j - i - 1));
    else       v = (unsigned)(pair_cum(j) + (i - j - 1)) | 0x8000u;
    ptab2[idx] = (unsigned short)v;
  }
  __syncthreads();
  if (t < IFEAT) {                             // combine sW partials
    float a = 0.0f;
    #pragma unroll
    for (int c = 0; c < 8; ++c) a += swpart[t * 8 + c];
    sW[t] = a;                                 // read in 4a (barriers cover)
  }

  // ---- phase 1: h1 = relu(x @ L1W^T + L1b), pack f16 -> sAtp(ss)[n][k2] ----
  {
    const int n = t & 31, gI = t >> 5, kb = gI * 8;
    float a[2][8];
    #pragma unroll
    for (int r = 0; r < 8; ++r) {
      const int k = kb + r;
      const float4 w = *(const float4*)(L1W + k * 4);   // shared across ss
      const float bias = L1b[k];
      #pragma unroll
      for (int ss = 0; ss < 2; ++ss) {
        const float* xv = sx + ss * 128 + n * 4;
        float v = bias;
        v = fmaf(xv[0], w.x, v); v = fmaf(xv[1], w.y, v);
        v = fmaf(xv[2], w.z, v); v = fmaf(xv[3], w.w, v);
        a[ss][r] = fmaxf(v, 0.0f);
      }
    }
    #pragma unroll
    for (int ss = 0; ss < 2; ++ss) {
      unsigned* sAtp = (unsigned*)(smem + ss * 1152);
      int4 pk;
      pk.x = (int)pbits(pack2(a[ss][0], a[ss][1]));
      pk.y = (int)pbits(pack2(a[ss][2], a[ss][3]));
      pk.z = (int)pbits(pack2(a[ss][4], a[ss][5]));
      pk.w = (int)pbits(pack2(a[ss][6], a[ss][7]));
      *(int4*)(sAtp + n * 36 + gI * 4) = pk;
    }
  }
  __syncthreads();

  const int lane = t & 63;
  const int wv   = t >> 6;        // wave id
  const int qd   = lane >> 4;     // quad 0..3
  const int ln   = lane & 15;

  // ---- phase 2: h2 = relu(h1 @ L2W^T + L2b) via MFMA; reg-buffer both ss,
  // then overwrite region A as sBtp(ss)[n][k2]. A-frags shared across ss. ----
  {
    const int m = 16 * wv + ln;
    const float* wr = L2W + m * HID;
    const f16x8 A0 = pack8(*(const float4*)(wr + 8 * qd),
                           *(const float4*)(wr + 8 * qd + 4));
    const f16x8 A1 = pack8(*(const float4*)(wr + 32 + 8 * qd),
                           *(const float4*)(wr + 32 + 8 * qd + 4));
    const float4 bias = *(const float4*)(L2b + 16 * wv + 4 * qd);
    unsigned pk[2][4];
    #pragma unroll
    for (int ss = 0; ss < 2; ++ss) {
      const unsigned* sAtp = (const unsigned*)(smem + ss * 1152);
      #pragma unroll
      for (int nt = 0; nt < 2; ++nt) {
        const int n = nt * 16 + ln;
        const f16x8 B0 = __builtin_bit_cast(f16x8, *(const int4*)(sAtp + n * 36 + 4 * qd));
        const f16x8 B1 = __builtin_bit_cast(f16x8, *(const int4*)(sAtp + n * 36 + 16 + 4 * qd));
        f32x4 c; c[0] = bias.x; c[1] = bias.y; c[2] = bias.z; c[3] = bias.w;
        c = __builtin_amdgcn_mfma_f32_16x16x32_f16(A0, B0, c, 0, 0, 0);
        c = __builtin_amdgcn_mfma_f32_16x16x32_f16(A1, B1, c, 0, 0, 0);
        pk[ss][nt * 2]     = pbits(pack2(fmaxf(c[0], 0.f), fmaxf(c[1], 0.f)));
        pk[ss][nt * 2 + 1] = pbits(pack2(fmaxf(c[2], 0.f), fmaxf(c[3], 0.f)));
      }
    }
    __syncthreads();   // all sAtp reads done before overwrite
    #pragma unroll
    for (int ss = 0; ss < 2; ++ss) {
      unsigned* sBtp = (unsigned*)(smem + ss * 1152);
      #pragma unroll
      for (int nt = 0; nt < 2; ++nt) {
        const int n = nt * 16 + ln;
        sBtp[n * 36 + 8 * wv + 2 * qd]     = pk[ss][nt * 2];
        sBtp[n * 36 + 8 * wv + 2 * qd + 1] = pk[ss][nt * 2 + 1];
      }
    }
  }
  __syncthreads();

  // ---- phase 3: g = h2 @ I1W^T via MFMA; store E = exp2(g') as f16 pairs ----
  {
    const int m = 16 * wv + ln;
    const float* wr = I1W + m * HID;
    const f16x8 A0 = pack8(*(const float4*)(wr + 8 * qd),
                           *(const float4*)(wr + 8 * qd + 4));
    const f16x8 A1 = pack8(*(const float4*)(wr + 32 + 8 * qd),
                           *(const float4*)(wr + 32 + 8 * qd + 4));
    #pragma unroll
    for (int ss = 0; ss < 2; ++ss) {
      const unsigned* sBtp = (const unsigned*)(smem + ss * 1152);
      unsigned* sEd = sEd0 + ss * 1152;
      #pragma unroll
      for (int nt = 0; nt < 2; ++nt) {
        const int n = nt * 16 + ln;
        const f16x8 B0 = __builtin_bit_cast(f16x8, *(const int4*)(sBtp + n * 36 + 4 * qd));
        const f16x8 B1 = __builtin_bit_cast(f16x8, *(const int4*)(sBtp + n * 36 + 16 + 4 * qd));
        f32x4 c; c[0] = 0.f; c[1] = 0.f; c[2] = 0.f; c[3] = 0.f;
        c = __builtin_amdgcn_mfma_f32_16x16x32_f16(A0, B0, c, 0, 0, 0);
        c = __builtin_amdgcn_mfma_f32_16x16x32_f16(A1, B1, c, 0, 0, 0);
        float e[4];
        #pragma unroll
        for (int r = 0; r < 4; ++r) {
          float gp = fminf(fmaxf(c[r] * TWO_LOG2E, -GP_CLAMP), GP_CLAMP);
          e[r] = EXP2F(gp);
        }
        // mo = 16wv+4qd+r; f16 idx n*72+mo -> dword n*36 + 8wv + 2qd + {0,1}
        sEd[n * 36 + 8 * wv + 2 * qd]     = pbits(pack2(e[0], e[1]));
        sEd[n * 36 + 8 * wv + 2 * qd + 1] = pbits(pack2(e[2], e[3]));
      }
    }
  }
  __syncthreads();   // region A + sE settled before 4a

  // ---- phase 4a: pair dots via MFMA, both ss per tile. All-f16 hot path:
  // A = fj * rcph(ei + fj); row offsets pre-multiplied in ptab32. ----
  {
    const f16x8 B0 = __builtin_bit_cast(f16x8, *(const int4*)(wB + ln * 32 + 4 * qd));
    const f16x8 B1 = __builtin_bit_cast(f16x8, *(const int4*)(wB + ln * 32 + 16 + 4 * qd));
    const float Wf = sW[ln & 7];

    for (int tile = wv; tile < NTILE; tile += 4) {
      const unsigned pij = ptab32[tile * 16 + ln];   // (i*36)<<16 | (j*36)
      const int io = (int)(pij >> 16), jo = (int)(pij & 0xffffu);
      #pragma unroll
      for (int ss = 0; ss < 2; ++ss) {
        const unsigned* sEd = sEd0 + ss * 1152;
        _Float16* sv = ss ? (_Float16*)(smem + 4608) : (_Float16*)smem;
        const f16x8 ei0 = __builtin_bit_cast(f16x8, *(const int4*)(sEd + io + 4 * qd));
        const f16x8 ei1 = __builtin_bit_cast(f16x8, *(const int4*)(sEd + io + 16 + 4 * qd));
        const f16x8 fj0 = __builtin_bit_cast(f16x8, *(const int4*)(sEd + jo + 4 * qd));
        const f16x8 fj1 = __builtin_bit_cast(f16x8, *(const int4*)(sEd + jo + 16 + 4 * qd));
        const f16x8 su0 = ei0 + fj0;               // v_pk_add_f16
        const f16x8 su1 = ei1 + fj1;
        f16x8 q0, q1;
        #pragma unroll
        for (int k = 0; k < 8; ++k) { q0[k] = RCPH(su0[k]); q1[k] = RCPH(su1[k]); }
        const f16x8 A0 = fj0 * q0;                 // v_pk_mul_f16; r in [0,1]
        const f16x8 A1 = fj1 * q1;
        f32x4 c; c[0] = 0.f; c[1] = 0.f; c[2] = 0.f; c[3] = 0.f;
        c = __builtin_amdgcn_mfma_f32_16x16x32_f16(A0, B0, c, 0, 0, 0);
        c = __builtin_amdgcn_mfma_f32_16x16x32_f16(A1, B1, c, 0, 0, 0);
        if (ln < IFEAT) {
          #pragma unroll
          for (int r = 0; r < 4; ++r) {
            const float v = tanh_u(fmaf(-2.0f, c[r], Wf));
            sv[(tile * 16 + 4 * qd + r) * 8 + ln] = (_Float16)v;
          }
        }
      }
    }
  }
  __syncthreads();   // sv complete; wB dead -> part may overwrite

  // ---- phase 4b: thread = (ss, i, d, half); table-driven gather ----
  {
    const int ss = t >> 7, i = (t >> 2) & 31, d = (t >> 1) & 1, half = t & 1;
    const _Float16* sv = ss ? (const _Float16*)(smem + 4608) : (const _Float16*)smem;
    const int msta = half * 16;
    const int mend = half ? 31 : 16;
    float sum = 0.0f;
    for (int m = msta; m < mend; ++m) {
      const unsigned pv = ptab2[i * 31 + m];       // q | sign<<15
      const int q = (int)(pv & 0x7fffu);
      const h2* vp = (const h2*)(sv + q * 8 + d * 4);
      const h2 va = vp[0], vb = vp[1];
      const float4 cf = *(const float4*)(I3 + (i * 31 + m) * 8 + d * 4);
      float dot;
      dot = cf.x * (float)va.x;
      dot = fmaf(cf.y, (float)va.y, dot);
      dot = fmaf(cf.z, (float)vb.x, dot);
      dot = fmaf(cf.w, (float)vb.y, dot);
      sum += (pv & 0x8000u) ? -dot : dot;
    }
    part[t] = sum;
  }
  __syncthreads();

  // ---- final: combine partials + self term + store (2 s x 64 outputs) ----
  if (t < 128) {
    const int ss = t >> 6, i = (t >> 1) & 31, d = t & 1;
    const int pbase = ss * 128 + i * 4 + d * 2;
    float sum = part[pbase] + part[pbase + 1];

    float res = S2b[i * 2 + d] + sum;
    const float* xv = sx + ss * 128 + i * 4;
    #pragma unroll
    for (int k = 0; k < 2; ++k) {
      const int f = d * 2 + k;
      float hs = S1b[f];
      hs = fmaf(xv[0], S1W[f * 4 + 0], hs);
      hs = fmaf(xv[1], S1W[f * 4 + 1], hs);
      hs = fmaf(xv[2], S1W[f * 4 + 2], hs);
      hs = fmaf(xv[3], S1W[f * 4 + 3], hs);
      hs = fmaxf(hs, 0.0f);
      res = fmaf(hs, S2W[i * 4 + d * 2 + k], res);
    }
    out[(s0 + ss) * (NOBJ * 2) + i * 2 + d] = res;
  }
}

extern "C" void kernel_launch(void* const* d_in, const int* in_sizes, int n_in,
                              void* d_out, int out_size, void* d_ws, size_t ws_size,
                              hipStream_t stream) {
  const float* x   = (const float*)d_in[0];
  const float* L1W = (const float*)d_in[1];
  const float* L1b = (const float*)d_in[2];
  const float* L2W = (const float*)d_in[3];
  const float* L2b = (const float*)d_in[4];
  const float* I1W = (const float*)d_in[5];
  const float* I2W = (const float*)d_in[6];
  const float* I3  = (const float*)d_in[7];
  const float* S1W = (const float*)d_in[8];
  const float* S1b = (const float*)d_in[9];
  const float* S2W = (const float*)d_in[10];
  const float* S2b = (const float*)d_in[11];
  float* outp = (float*)d_out;

  magnet_fused<<<SEQ / 2, 256, 0, stream>>>(x, L1W, L1b, L2W, L2b, I1W, I2W, I3,
                                            S1W, S1b, S2W, S2b, outp);
}